// Round 15
// baseline (2194.725 us; speedup 1.0000x reference)
//
#include <hip/hip_runtime.h>
#include <math.h>

// ---------------------------------------------------------------------------
// GRUFeatureExtractor — bf16 MFMA everywhere, fused GRU steps.
//   R15: big-GEMM retile 256x256 -> 128x128 dbuf (64KB LDS -> 2 blocks/CU =
//   4 waves/SIMD; R14's 128KB tile was 1 block/CU, 2 waves/SIMD — not enough
//   TLP to hide lgkm chains). Counted-vmcnt(8) loop + T2 swizzle retained
//   byte-for-byte. P0P1/OC moved onto the pipelined kernel. T5 setprio
//   around MFMA clusters in gemm_mfma128p + gru_step.
// ---------------------------------------------------------------------------

#define SEQ 10

typedef unsigned short bf16u;
typedef __attribute__((ext_vector_type(8))) short short8v;   // 8 bf16
typedef __attribute__((ext_vector_type(4))) float f32x4;     // MFMA C/D

#define AS1 __attribute__((address_space(1)))
#define AS3 __attribute__((address_space(3)))

__device__ __forceinline__ float b2f(bf16u u) {
    union { unsigned int i; float f; } v; v.i = ((unsigned int)u) << 16; return v.f;
}
__device__ __forceinline__ bf16u f2b(float f) {
    union { float f; unsigned int i; } v; v.f = f;
    unsigned int r = (v.i + 0x7FFFu + ((v.i >> 16) & 1u)) >> 16;
    return (bf16u)r;
}
__device__ __forceinline__ float fast_sigm(float x) { return 1.0f / (1.0f + __expf(-x)); }
__device__ __forceinline__ float fast_tanh(float x) {
    float e = __expf(-2.0f * x);
    return 2.0f / (1.0f + e) - 1.0f;
}

__global__ void cvt_f2b(const float* __restrict__ src, bf16u* __restrict__ dst, int n4)
{
    int i = blockIdx.x * 256 + threadIdx.x;
    if (i < n4) {
        float4 v = ((const float4*)src)[i];
        ushort4 u; u.x = f2b(v.x); u.y = f2b(v.y); u.z = f2b(v.z); u.w = f2b(v.w);
        ((ushort4*)dst)[i] = u;
    }
}

// ---------------------------------------------------------------------------
// 128x128 counted-vmcnt double-buffered MFMA GEMM (4 waves, 64x64/wave),
// T2 swizzle (pre-swizzled global source + XOR read), T5 setprio on MFMA.
// LDS 64KB -> 2 blocks/CU. Requires M%128==N%128==0, K%64==0, K>=128.
// ---------------------------------------------------------------------------
template <typename TC>
__global__ __launch_bounds__(256) void gemm_mfma128p(
    const bf16u* __restrict__ A, long long sAz, int lda,
    const bf16u* __restrict__ W, long long sWz,
    const float* __restrict__ bias, long long sBz,
    TC* __restrict__ C, long long sCz, int ldc,
    int K, int act)
{
    __shared__ bf16u As[2][128 * 64];
    __shared__ bf16u Ws[2][128 * 64];

    const int z = blockIdx.z;
    A += (long long)z * sAz;
    W += (long long)z * sWz;
    C += (long long)z * sCz;
    const float* bz = bias ? (bias + (long long)z * sBz) : nullptr;

    // T1: bijective XCD swizzle
    const int gx = gridDim.x;
    const int nwg = gx * gridDim.y;
    const int orig = blockIdx.y * gx + blockIdx.x;
    const int q = nwg >> 3, rres = nwg & 7;
    const int xcd = orig & 7, loc = orig >> 3;
    const int wgid = (xcd < rres ? xcd * (q + 1) : rres * (q + 1) + (xcd - rres) * q) + loc;
    const int bm = (wgid / gx) * 128;
    const int bn = (wgid % gx) * 128;

    const int tid = threadIdx.x;
    const int lane = tid & 63;
    const int w = tid >> 6;          // 0..3
    const int wm = w >> 1;           // 0..1
    const int wn = w & 1;            // 0..1
    const int l15 = lane & 15;
    const int lk8 = (lane >> 4) * 8;
    const int swz = (l15 & 7) << 3;

    f32x4 acc[4][4];
#pragma unroll
    for (int i = 0; i < 4; ++i)
#pragma unroll
        for (int j = 0; j < 4; ++j)
#pragma unroll
            for (int r = 0; r < 4; ++r) acc[i][j][r] = 0.0f;

    const int srow = lane >> 3;
    const int scol = ((lane & 7) ^ srow) * 8;   // T2 pre-swizzled source slot
    const bf16u* Ag[4];
    const bf16u* Wg[4];
    int loff[4];
#pragma unroll
    for (int p = 0; p < 4; ++p) {
        const int r = p * 32 + w * 8 + srow;
        Ag[p] = A + (long long)(bm + r) * lda + scol;
        Wg[p] = W + (long long)(bn + r) * K + scol;
        loff[p] = (p * 32 + w * 8) * 64;        // wave-uniform LDS base (elems)
    }

    auto stage = [&](int kt, int b) {
        const long long k1 = (long long)kt << 6;
#pragma unroll
        for (int p = 0; p < 4; ++p) {
            __builtin_amdgcn_global_load_lds((const AS1 void*)(Ag[p] + k1),
                (AS3 void*)(&As[b][loff[p]]), 16, 0, 0);
            __builtin_amdgcn_global_load_lds((const AS1 void*)(Wg[p] + k1),
                (AS3 void*)(&Ws[b][loff[p]]), 16, 0, 0);
        }
    };
    auto compute = [&](int b) {
#pragma unroll
        for (int ks = 0; ks < 2; ++ks) {
            const int ko = (ks * 32 + lk8) ^ swz;
            short8v af[4], bfr[4];
#pragma unroll
            for (int i = 0; i < 4; ++i)
                af[i] = *(const short8v*)(&As[b][(wm * 64 + i * 16 + l15) * 64 + ko]);
#pragma unroll
            for (int i = 0; i < 4; ++i)
                bfr[i] = *(const short8v*)(&Ws[b][(wn * 64 + i * 16 + l15) * 64 + ko]);
            __builtin_amdgcn_s_setprio(1);
#pragma unroll
            for (int mi = 0; mi < 4; ++mi)
#pragma unroll
                for (int ni = 0; ni < 4; ++ni)
                    acc[mi][ni] = __builtin_amdgcn_mfma_f32_16x16x32_bf16(
                        af[mi], bfr[ni], acc[mi][ni], 0, 0, 0);
            __builtin_amdgcn_s_setprio(0);
        }
    };

    const int nt = K >> 6;

    stage(0, 0);
    stage(1, 1);

    for (int t = 0; t < nt - 1; ++t) {
        asm volatile("s_waitcnt vmcnt(8)" ::: "memory");
        __builtin_amdgcn_s_barrier();
        asm volatile("" ::: "memory");
        compute(t & 1);
        asm volatile("" ::: "memory");
        __builtin_amdgcn_s_barrier();
        if (t + 2 < nt) stage(t + 2, t & 1);
    }
    asm volatile("s_waitcnt vmcnt(0)" ::: "memory");
    __builtin_amdgcn_s_barrier();
    compute((nt - 1) & 1);

    const int r0 = (lane >> 4) * 4;
#pragma unroll
    for (int mi = 0; mi < 4; ++mi) {
#pragma unroll
        for (int ni = 0; ni < 4; ++ni) {
            const int col = bn + wn * 64 + ni * 16 + l15;
            float badd = bz ? bz[col] : 0.0f;
#pragma unroll
            for (int r = 0; r < 4; ++r) {
                const long long row = bm + wm * 64 + mi * 16 + r0 + r;
                float v = acc[mi][ni][r] + badd;
                if (act) v = tanhf(v);
                if constexpr (sizeof(TC) == 4) ((float*)C)[row * ldc + col] = v;
                else                           ((bf16u*)C)[row * ldc + col] = f2b(v);
            }
        }
    }
}

// ---------------------------------------------------------------------------
// 128x128 MFMA GEMM (R7-verified single-buffer; small dispatches only).
// ---------------------------------------------------------------------------
template <typename TC>
__global__ __launch_bounds__(256) void gemm_mfma(
    const bf16u* __restrict__ A, long long sAz, int lda,
    const bf16u* __restrict__ W, long long sWz,
    const float* __restrict__ bias, long long sBz,
    TC* __restrict__ C, long long sCz, int ldc,
    int K, int act)
{
    __shared__ bf16u As[128 * 64];
    __shared__ bf16u Ws[128 * 64];

    const int z = blockIdx.z;
    A += (long long)z * sAz;
    W += (long long)z * sWz;
    C += (long long)z * sCz;
    const float* bz = bias ? (bias + (long long)z * sBz) : nullptr;

    const int gx = gridDim.x;
    const int nwg = gx * gridDim.y;
    const int orig = blockIdx.y * gx + blockIdx.x;
    const int q = nwg >> 3, rres = nwg & 7;
    const int xcd = orig & 7, loc = orig >> 3;
    const int wgid = (xcd < rres ? xcd * (q + 1) : rres * (q + 1) + (xcd - rres) * q) + loc;
    const int bm = (wgid / gx) * 128;
    const int bn = (wgid % gx) * 128;

    const int tid = threadIdx.x;
    const int lane = tid & 63;
    const int wave = tid >> 6;
    const int wr = (wave >> 1) * 64;
    const int wc = (wave & 1) * 64;
    const int l15 = lane & 15;
    const int lk8 = (lane >> 4) * 8;

    f32x4 acc[4][4];
#pragma unroll
    for (int i = 0; i < 4; ++i)
#pragma unroll
        for (int j = 0; j < 4; ++j)
#pragma unroll
            for (int r = 0; r < 4; ++r) acc[i][j][r] = 0.0f;

    const int sr = wave * 32 + (lane >> 3);
    const int sc = (lane & 7) * 8;
    const bf16u* Ag = A + (long long)(bm + sr) * lda + sc;
    const bf16u* Wg = W + (long long)(bn + sr) * K + sc;
    bf16u* Al = As + wave * 32 * 64;
    bf16u* Wl = Ws + wave * 32 * 64;

    for (int k0 = 0; k0 < K; k0 += 64) {
#pragma unroll
        for (int p = 0; p < 4; ++p) {
            __builtin_amdgcn_global_load_lds(
                (const AS1 void*)(Ag + k0 + (long long)(8 * p) * lda),
                (AS3 void*)(Al + 8 * p * 64), 16, 0, 0);
            __builtin_amdgcn_global_load_lds(
                (const AS1 void*)(Wg + k0 + (long long)(8 * p) * K),
                (AS3 void*)(Wl + 8 * p * 64), 16, 0, 0);
        }
        __syncthreads();
#pragma unroll
        for (int ks = 0; ks < 2; ++ks) {
            short8v af[4], bfr[4];
#pragma unroll
            for (int i = 0; i < 4; ++i)
                af[i] = *(const short8v*)(As + (wr + i * 16 + l15) * 64 + ks * 32 + lk8);
#pragma unroll
            for (int i = 0; i < 4; ++i)
                bfr[i] = *(const short8v*)(Ws + (wc + i * 16 + l15) * 64 + ks * 32 + lk8);
#pragma unroll
            for (int mi = 0; mi < 4; ++mi)
#pragma unroll
                for (int ni = 0; ni < 4; ++ni)
                    acc[mi][ni] = __builtin_amdgcn_mfma_f32_16x16x32_bf16(
                        af[mi], bfr[ni], acc[mi][ni], 0, 0, 0);
        }
        __syncthreads();
    }

    const int r0 = (lane >> 4) * 4;
#pragma unroll
    for (int mi = 0; mi < 4; ++mi) {
#pragma unroll
        for (int ni = 0; ni < 4; ++ni) {
            const int col = bn + wc + ni * 16 + l15;
            float badd = bz ? bz[col] : 0.0f;
#pragma unroll
            for (int r = 0; r < 4; ++r) {
                const long long row = bm + wr + mi * 16 + r0 + r;
                float v = acc[mi][ni][r] + badd;
                if (act) v = tanhf(v);
                if constexpr (sizeof(TC) == 4) ((float*)C)[row * ldc + col] = v;
                else                           ((bf16u*)C)[row * ldc + col] = f2b(v);
            }
        }
    }
}

// ---------------------------------------------------------------------------
// FUSED GRU step (R14 verified: counted-vmcnt dbuf + T2 swizzle) + T5 setprio.
// 64M x 32N x 3 gates, BK=64, 8 K-tiles, LDS 40KB -> 4 blocks/CU.
// ---------------------------------------------------------------------------
template <int LAYER, bool FIRST>
__global__ __launch_bounds__(256) void gru_step(
    const bf16u* __restrict__ Hb,
    const bf16u* __restrict__ Whh,
    const float* __restrict__ bhh,
    const bf16u* __restrict__ P0,
    const bf16u* __restrict__ P1,
    const float* __restrict__ bih,
    const bf16u* __restrict__ GIT,
    const float* __restrict__ hprev,
    float* __restrict__ hnext,
    bf16u* __restrict__ hnextb,
    bf16u* __restrict__ hout,
    int t, int CB)
{
    __shared__ bf16u As[2][64 * 64];
    __shared__ bf16u Ws[2][96 * 64];

    const int z = blockIdx.z;
    const int bn = blockIdx.x * 32;
    const int bm = blockIdx.y * 64;
    const int tid = threadIdx.x;
    const int lane = tid & 63;
    const int wave = tid >> 6;
    const int wm = wave >> 1;
    const int wn = wave & 1;
    const int l15 = lane & 15;
    const int lk8 = (lane >> 4) * 8;
    const int swz = (l15 & 7) << 3;

    f32x4 acc[3][2];
#pragma unroll
    for (int g = 0; g < 3; ++g)
#pragma unroll
        for (int i = 0; i < 2; ++i)
#pragma unroll
            for (int r = 0; r < 4; ++r) acc[g][i][r] = 0.0f;

    if constexpr (!FIRST) {
        const bf16u* hsrc = Hb + (long long)z * CB * 512;
        const bf16u* wsrc = Whh + (long long)z * 1536 * 512;

        const int srow = lane >> 3;
        const int sc = ((lane & 7) ^ srow) * 8;   // T2 pre-swizzled source
        const bf16u* Ag = hsrc + (long long)(bm + 16 * wave + srow) * 512 + sc;
        const bf16u* Wg[3];
#pragma unroll
        for (int p = 0; p < 3; ++p) {
            const int lr = 24 * wave + 8 * p + srow;
            const int g = lr >> 5, c = lr & 31;
            Wg[p] = wsrc + (long long)(g * 512 + bn + c) * 512 + sc;
        }

        auto stage = [&](int kt, int b) {
            const long long k0 = (long long)kt << 6;
#pragma unroll
            for (int p = 0; p < 2; ++p)
                __builtin_amdgcn_global_load_lds(
                    (const AS1 void*)(Ag + k0 + (long long)(8 * p) * 512),
                    (AS3 void*)(&As[b][(16 * wave + 8 * p) * 64]), 16, 0, 0);
#pragma unroll
            for (int p = 0; p < 3; ++p)
                __builtin_amdgcn_global_load_lds(
                    (const AS1 void*)(Wg[p] + k0),
                    (AS3 void*)(&Ws[b][(24 * wave + 8 * p) * 64]), 16, 0, 0);
        };
        auto compute = [&](int b) {
#pragma unroll
            for (int ks = 0; ks < 2; ++ks) {
                const int ko = (ks * 32 + lk8) ^ swz;
                short8v af[2], bf[3];
#pragma unroll
                for (int mi = 0; mi < 2; ++mi)
                    af[mi] = *(const short8v*)(&As[b][(wm * 32 + mi * 16 + l15) * 64 + ko]);
#pragma unroll
                for (int g = 0; g < 3; ++g)
                    bf[g] = *(const short8v*)(&Ws[b][(g * 32 + wn * 16 + l15) * 64 + ko]);
                __builtin_amdgcn_s_setprio(1);
#pragma unroll
                for (int g = 0; g < 3; ++g)
#pragma unroll
                    for (int mi = 0; mi < 2; ++mi)
                        acc[g][mi] = __builtin_amdgcn_mfma_f32_16x16x32_bf16(
                            af[mi], bf[g], acc[g][mi], 0, 0, 0);
                __builtin_amdgcn_s_setprio(0);
            }
        };

        stage(0, 0);
        stage(1, 1);
        for (int kt = 0; kt < 7; ++kt) {
            asm volatile("s_waitcnt vmcnt(5)" ::: "memory");
            __builtin_amdgcn_s_barrier();
            asm volatile("" ::: "memory");
            compute(kt & 1);
            asm volatile("" ::: "memory");
            __builtin_amdgcn_s_barrier();
            if (kt + 2 < 8) stage(kt + 2, kt & 1);
        }
        asm volatile("s_waitcnt vmcnt(0)" ::: "memory");
        __builtin_amdgcn_s_barrier();
        compute(1);
    }

    const int r0 = (lane >> 4) * 4;
    const int s = z ? (SEQ - 1 - t) : t;
    float c0 = 0.0f, c1 = 0.0f;
    if (LAYER == 0) {
        float ph = 0.6283185307179586f * (float)s;
        c0 = 1.0f + 0.1f * cosf(ph);
        c1 = 0.05f * sinf(ph);
    }

    const int j = bn + wn * 16 + l15;
    const float bh0 = bhh[z * 1536 + j];
    const float bh1 = bhh[z * 1536 + 512 + j];
    const float bh2 = bhh[z * 1536 + 1024 + j];
    float bi0 = 0, bi1 = 0, bi2 = 0;
    if (LAYER == 0) {
        bi0 = bih[z * 1536 + j];
        bi1 = bih[z * 1536 + 512 + j];
        bi2 = bih[z * 1536 + 1024 + j];
    }

#pragma unroll
    for (int mi = 0; mi < 2; ++mi) {
#pragma unroll
        for (int rr = 0; rr < 4; ++rr) {
            const int m = bm + wm * 32 + mi * 16 + r0 + rr;
            float gr = acc[0][mi][rr] + bh0;
            float gz = acc[1][mi][rr] + bh1;
            float gn = acc[2][mi][rr] + bh2;
            float ir, iz, inn;
            if (LAYER == 0) {
                const bf16u* p0 = P0 + (long long)m * 3072 + z * 1536 + j;
                const bf16u* p1 = P1 + (long long)m * 3072 + z * 1536 + j;
                ir  = c0 * b2f(p0[0])    + c1 * b2f(p1[0])    + bi0;
                iz  = c0 * b2f(p0[512])  + c1 * b2f(p1[512])  + bi1;
                inn = c0 * b2f(p0[1024]) + c1 * b2f(p1[1024]) + bi2;
            } else {
                const bf16u* gi = GIT + (((long long)z * CB + m) * SEQ + s) * 1536 + j;
                ir = b2f(gi[0]); iz = b2f(gi[512]); inn = b2f(gi[1024]);
            }
            const long long ho = ((long long)z * CB + m) * 512 + j;
            float r  = fast_sigm(ir + gr);
            float zz = fast_sigm(iz + gz);
            float n  = fast_tanh(inn + r * gn);
            float hnew;
            if constexpr (FIRST) hnew = (1.0f - zz) * n;
            else                 hnew = (1.0f - zz) * n + zz * hprev[ho];
            hnext[ho]  = hnew;
            hnextb[ho] = f2b(hnew);
            hout[((long long)m * SEQ + s) * 1024 + z * 512 + j] = f2b(hnew);
        }
    }
}

__global__ void roll_b(const bf16u* __restrict__ xp, bf16u* __restrict__ rl)
{
    int idx = blockIdx.x * 256 + threadIdx.x;
    int i = idx & 511;
    int b = idx >> 9;
    rl[(size_t)b * 512 + i] = xp[(size_t)b * 512 + ((i + 511) & 511)];
}

// fused attention per (b_local, head): SEQ=10, HD=128; fp32 math, bf16 I/O
__global__ __launch_bounds__(128) void attn_kernel(const bf16u* __restrict__ qkv,
                                                   bf16u* __restrict__ o)
{
    const int bh = blockIdx.x;
    const int h = bh & 7;
    const int bl = bh >> 3;
    const int tid = threadIdx.x;

    __shared__ float Q[SEQ][128], Kx[SEQ][128], V[SEQ][128], Amat[SEQ][SEQ];

    const bf16u* base = qkv + (size_t)bl * SEQ * 3072 + h * 128;
#pragma unroll
    for (int s = 0; s < SEQ; ++s) {
        Q[s][tid]  = b2f(base[s * 3072 + tid]);
        Kx[s][tid] = b2f(base[s * 3072 + 1024 + tid]);
        V[s][tid]  = b2f(base[s * 3072 + 2048 + tid]);
    }
    __syncthreads();

    if (tid < SEQ * SEQ) {
        int q = tid / SEQ, k = tid % SEQ;
        float acc = 0.0f;
#pragma unroll 8
        for (int d0 = 0; d0 < 128; ++d0) acc += Q[q][d0] * Kx[k][d0];
        Amat[q][k] = acc * 0.08838834764831845f;
    }
    __syncthreads();

    if (tid < SEQ) {
        float m = -1e30f;
#pragma unroll
        for (int k = 0; k < SEQ; ++k) m = fmaxf(m, Amat[tid][k]);
        float e[SEQ], ssum = 0.0f;
#pragma unroll
        for (int k = 0; k < SEQ; ++k) { e[k] = expf(Amat[tid][k] - m); ssum += e[k]; }
        float inv = 1.0f / ssum;
#pragma unroll
        for (int k = 0; k < SEQ; ++k) Amat[tid][k] = e[k] * inv;
    }
    __syncthreads();

    bf16u* ob = o + (size_t)bl * SEQ * 1024 + h * 128;
#pragma unroll
    for (int q = 0; q < SEQ; ++q) {
        float acc = 0.0f;
#pragma unroll
        for (int k = 0; k < SEQ; ++k) acc += Amat[q][k] * V[k][tid];
        ob[q * 1024 + tid] = f2b(acc);
    }
}

// agg[b][j] = 0.1 * sum_s (go[b][s][j] + ao[b][s][j]); 4 el/thread, bf16 out
__global__ void mean_kernel(const bf16u* __restrict__ go, const bf16u* __restrict__ ao,
                            bf16u* __restrict__ agg)
{
    int idx = blockIdx.x * 256 + threadIdx.x;
    int j4 = (idx & 255) * 4;
    int bl = idx >> 8;
    const bf16u* g = go + (size_t)bl * (SEQ * 1024) + j4;
    const bf16u* a = ao + (size_t)bl * (SEQ * 1024) + j4;
    float s0 = 0, s1 = 0, s2 = 0, s3 = 0;
#pragma unroll
    for (int t = 0; t < SEQ; ++t) {
        ushort4 gv = *(const ushort4*)(g + t * 1024);
        ushort4 av = *(const ushort4*)(a + t * 1024);
        s0 += b2f(gv.x) + b2f(av.x);
        s1 += b2f(gv.y) + b2f(av.y);
        s2 += b2f(gv.z) + b2f(av.z);
        s3 += b2f(gv.w) + b2f(av.w);
    }
    ushort4 u; u.x = f2b(0.1f * s0); u.y = f2b(0.1f * s1); u.z = f2b(0.1f * s2); u.w = f2b(0.1f * s3);
    *(ushort4*)(agg + (size_t)bl * 1024 + j4) = u;
}

extern "C" void kernel_launch(void* const* d_in, const int* in_sizes, int n_in,
                              void* d_out, int out_size, void* d_ws, size_t ws_size,
                              hipStream_t stream)
{
    const float* x    = (const float*)d_in[0];
    const float* Wp   = (const float*)d_in[1];
    const float* bp   = (const float*)d_in[2];
    const float* Wih0 = (const float*)d_in[3];
    const float* Whh0 = (const float*)d_in[4];
    const float* bih0 = (const float*)d_in[5];
    const float* bhh0 = (const float*)d_in[6];
    const float* Wih1 = (const float*)d_in[7];
    const float* Whh1 = (const float*)d_in[8];
    const float* bih1 = (const float*)d_in[9];
    const float* bhh1 = (const float*)d_in[10];
    const float* ipw  = (const float*)d_in[11];
    const float* ipb  = (const float*)d_in[12];
    const float* opw  = (const float*)d_in[13];
    const float* opb  = (const float*)d_in[14];
    const float* W1   = (const float*)d_in[15];
    const float* b1   = (const float*)d_in[16];
    const float* W2   = (const float*)d_in[17];
    const float* b2   = (const float*)d_in[18];
    float* out = (float*)d_out;

    const long long WOVER = 9437184LL;
    const long long WALL  = 24969216LL;
    int CB = 0;
    for (int c = 4096; c >= 128; c >>= 1)
        if (WOVER + (long long)c * 114688 <= (long long)ws_size) { CB = c; break; }
    if (CB == 0) return;
    const bool resident = (WALL + (long long)CB * 114688 <= (long long)ws_size);
    const long long WB = resident ? WALL : WOVER;
    const int CBA = CB / 2;

    bf16u* wreg = (bf16u*)d_ws;
    bf16u *Wpb, *Wih0b, *Whh0b, *Wih1b, *Whh1b, *ipwb, *opwb, *W1b, *W2b;
    if (resident) {
        Wpb   = wreg;
        Wih0b = wreg + 262144;
        Whh0b = wreg + 1835008;
        Wih1b = wreg + 3407872;
        Whh1b = wreg + 6553600;
        ipwb  = wreg + 8126464;
        opwb  = wreg + 11272192;
        W1b   = wreg + 12320768;
        W2b   = wreg + 12451840;
    } else {
        Wpb   = wreg;
        Wih0b = wreg + 262144;
        Whh0b = wreg + 1835008;
        Wih1b = wreg;
        Whh1b = wreg + 3145728;
        ipwb  = wreg;
        opwb  = wreg + 3145728;
        W1b   = wreg + 4194304;
        W2b   = wreg + 4325376;
    }

    char* A0 = (char*)d_ws + WB;
    bf16u* H1c = (bf16u*)A0;
    bf16u* GOc = (bf16u*)(A0 + 20480LL * CB);
    char*  U   = A0 + 40960LL * CB;
    bf16u* P0    = (bf16u*)U;
    bf16u* P1    = (bf16u*)(U + 6144LL * CB);
    bf16u* XB    = (bf16u*)(U + 12288LL * CB);
    bf16u* XPb   = (bf16u*)(U + 13312LL * CB);
    bf16u* RLb   = (bf16u*)(U + 14336LL * CB);
    bf16u* GIT   = (bf16u*)U;
    char*  HC    = U + 61440LL * CB;
    bf16u* QKV   = (bf16u*)U;
    bf16u* OC    = (bf16u*)(U + 61440LL * CB);
    bf16u* AOC   = (bf16u*)A0;
    bf16u* AGGb  = (bf16u*)(A0 + 10240LL * CB);
    bf16u* HIDb  = (bf16u*)(A0 + 12288LL * CB);

    const dim3 blk(256);
    const int MB = CB / 128;

    auto cvt = [&](const float* s, bf16u* d, long long nfloats) {
        int n4 = (int)(nfloats / 4);
        cvt_f2b<<<(n4 + 255) / 256, blk, 0, stream>>>(s, d, n4);
    };

    if (resident) {
        cvt(Wp,   Wpb,   512LL * 512);
        cvt(Wih0, Wih0b, 2LL * 1536 * 512);
        cvt(Whh0, Whh0b, 2LL * 1536 * 512);
        cvt(Wih1, Wih1b, 2LL * 1536 * 1024);
        cvt(Whh1, Whh1b, 2LL * 1536 * 512);
        cvt(ipw,  ipwb,  3072LL * 1024);
        cvt(opw,  opwb,  1024LL * 1024);
        cvt(W1,   W1b,   128LL * 1024);
        cvt(W2,   W2b,   256LL * 128);
    }

    for (int c0 = 0; c0 < 4096; c0 += CB) {
        // ---------------- phase A: preproc + layer-0 biGRU ----------------
        cvt(x + (long long)c0 * 512, XB, (long long)CB * 512);
        if (!resident) {
            cvt(Wp,   Wpb,   512LL * 512);
            cvt(Wih0, Wih0b, 2LL * 1536 * 512);
            cvt(Whh0, Whh0b, 2LL * 1536 * 512);
        }

        gemm_mfma<bf16u><<<dim3(4, MB, 1), blk, 0, stream>>>(
            XB, 0, 512, Wpb, 0, bp, 0, XPb, 0, 512, 512, 0);
        roll_b<<<CB * 2, blk, 0, stream>>>(XPb, RLb);
        gemm_mfma128p<bf16u><<<dim3(24, MB, 2), blk, 0, stream>>>(
            XPb, (long long)CB * 512, 512, Wih0b, 0, nullptr, 0,
            P0, (long long)CB * 3072, 3072, 512, 0);

        for (int t = 0; t < SEQ; ++t) {
            const int rb = t & 1;
            float* hprev  = (float*)(HC + (long long)rb * 6144 * CB);
            bf16u* Hbr    = (bf16u*)(HC + (long long)rb * 6144 * CB + 4096LL * CB);
            float* hnext  = (float*)(HC + (long long)(1 - rb) * 6144 * CB);
            bf16u* hnextb = (bf16u*)(HC + (long long)(1 - rb) * 6144 * CB + 4096LL * CB);
            if (t == 0)
                gru_step<0, true><<<dim3(16, CB / 64, 2), blk, 0, stream>>>(
                    Hbr, Whh0b, bhh0, P0, P1, bih0, nullptr,
                    hprev, hnext, hnextb, H1c, t, CB);
            else
                gru_step<0, false><<<dim3(16, CB / 64, 2), blk, 0, stream>>>(
                    Hbr, Whh0b, bhh0, P0, P1, bih0, nullptr,
                    hprev, hnext, hnextb, H1c, t, CB);
        }

        // ---------------- phase B: layer-1 biGRU ----------------
        if (!resident) {
            cvt(Wih1, Wih1b, 2LL * 1536 * 1024);
            cvt(Whh1, Whh1b, 2LL * 1536 * 512);
        }
        gemm_mfma128p<bf16u><<<dim3(12, MB * 10, 2), blk, 0, stream>>>(
            H1c, 0, 1024, Wih1b, 1536LL * 1024, bih1, 1536,
            GIT, (long long)CB * SEQ * 1536, 1536, 1024, 0);

        for (int t = 0; t < SEQ; ++t) {
            const int rb = t & 1;
            float* hprev  = (float*)(HC + (long long)rb * 6144 * CB);
            bf16u* Hbr    = (bf16u*)(HC + (long long)rb * 6144 * CB + 4096LL * CB);
            float* hnext  = (float*)(HC + (long long)(1 - rb) * 6144 * CB);
            bf16u* hnextb = (bf16u*)(HC + (long long)(1 - rb) * 6144 * CB + 4096LL * CB);
            if (t == 0)
                gru_step<1, true><<<dim3(16, CB / 64, 2), blk, 0, stream>>>(
                    Hbr, Whh1b, bhh1, nullptr, nullptr, nullptr, GIT,
                    hprev, hnext, hnextb, GOc, t, CB);
            else
                gru_step<1, false><<<dim3(16, CB / 64, 2), blk, 0, stream>>>(
                    Hbr, Whh1b, bhh1, nullptr, nullptr, nullptr, GIT,
                    hprev, hnext, hnextb, GOc, t, CB);
        }

        // ---------------- phase C: attention + head ----------------
        if (!resident) {
            cvt(ipw, ipwb, 3072LL * 1024);
            cvt(opw, opwb, 1024LL * 1024);
            cvt(W1,  W1b,  128LL * 1024);
            cvt(W2,  W2b,  256LL * 128);
        }
        gemm_mfma128p<bf16u><<<dim3(24, MB * 10, 1), blk, 0, stream>>>(
            GOc, 0, 1024, ipwb, 0, ipb, 0, QKV, 0, 3072, 1024, 0);
        for (int a0 = 0; a0 < CB; a0 += CBA) {
            attn_kernel<<<CBA * 8, dim3(128), 0, stream>>>(
                QKV + (long long)a0 * 30720, OC);
            gemm_mfma128p<bf16u><<<dim3(8, CBA * 10 / 128, 1), blk, 0, stream>>>(
                OC, 0, 1024, opwb, 0, opb, 0, AOC, 0, 1024, 1024, 0);
            mean_kernel<<<CBA, blk, 0, stream>>>(
                GOc + (long long)a0 * 10240, AOC, AGGb + (long long)a0 * 1024);
        }
        gemm_mfma<bf16u><<<dim3(1, MB, 1), blk, 0, stream>>>(
            AGGb, 0, 1024, W1b, 0, b1, 0, HIDb, 0, 128, 1024, 1);
        gemm_mfma<float><<<dim3(2, MB, 1), blk, 0, stream>>>(
            HIDb, 0, 128, W2b, 0, b2, 0, out + (long long)c0 * 256, 0, 256, 128, 0);
    }
}

// Round 16
// 2123.091 us; speedup vs baseline: 1.0337x; 1.0337x over previous
//
#include <hip/hip_runtime.h>
#include <math.h>

// ---------------------------------------------------------------------------
// GRUFeatureExtractor — bf16 MFMA everywhere, fused GRU steps.
//   R16: routing fix. GIT/QKV back on gemm_mfma256 (R14-verified 256x256
//   T2+T4 kernel: 207us, 0 bank conflicts, FETCH 103MB — 128x128 retile cost
//   +43us/dispatch from 2.2x fetch + 2x staging VALU). P0P1/OC stay on
//   gemm_mfma128p (their grids underfill at 256²). gru_step keeps setprio.
// ---------------------------------------------------------------------------

#define SEQ 10

typedef unsigned short bf16u;
typedef __attribute__((ext_vector_type(8))) short short8v;   // 8 bf16
typedef __attribute__((ext_vector_type(4))) float f32x4;     // MFMA C/D

#define AS1 __attribute__((address_space(1)))
#define AS3 __attribute__((address_space(3)))

__device__ __forceinline__ float b2f(bf16u u) {
    union { unsigned int i; float f; } v; v.i = ((unsigned int)u) << 16; return v.f;
}
__device__ __forceinline__ bf16u f2b(float f) {
    union { float f; unsigned int i; } v; v.f = f;
    unsigned int r = (v.i + 0x7FFFu + ((v.i >> 16) & 1u)) >> 16;
    return (bf16u)r;
}
__device__ __forceinline__ float fast_sigm(float x) { return 1.0f / (1.0f + __expf(-x)); }
__device__ __forceinline__ float fast_tanh(float x) {
    float e = __expf(-2.0f * x);
    return 2.0f / (1.0f + e) - 1.0f;
}

__global__ void cvt_f2b(const float* __restrict__ src, bf16u* __restrict__ dst, int n4)
{
    int i = blockIdx.x * 256 + threadIdx.x;
    if (i < n4) {
        float4 v = ((const float4*)src)[i];
        ushort4 u; u.x = f2b(v.x); u.y = f2b(v.y); u.z = f2b(v.z); u.w = f2b(v.w);
        ((ushort4*)dst)[i] = u;
    }
}

// ---------------------------------------------------------------------------
// 256x256 counted-vmcnt double-buffered MFMA GEMM (8 waves, 128x64/wave),
// T2 swizzle (pre-swizzled global source + XOR read). R14-verified: 207us,
// 0 bank conflicts on GIT/QKV shapes. LDS 128KB.
// ---------------------------------------------------------------------------
template <typename TC>
__global__ __launch_bounds__(512) void gemm_mfma256(
    const bf16u* __restrict__ A, long long sAz, int lda,
    const bf16u* __restrict__ W, long long sWz,
    const float* __restrict__ bias, long long sBz,
    TC* __restrict__ C, long long sCz, int ldc,
    int K, int act)
{
    __shared__ bf16u As[2][256 * 64];
    __shared__ bf16u Ws[2][256 * 64];

    const int z = blockIdx.z;
    A += (long long)z * sAz;
    W += (long long)z * sWz;
    C += (long long)z * sCz;
    const float* bz = bias ? (bias + (long long)z * sBz) : nullptr;

    const int gx = gridDim.x;
    const int nwg = gx * gridDim.y;
    const int orig = blockIdx.y * gx + blockIdx.x;
    const int q = nwg >> 3, rres = nwg & 7;
    const int xcd = orig & 7, loc = orig >> 3;
    const int wgid = (xcd < rres ? xcd * (q + 1) : rres * (q + 1) + (xcd - rres) * q) + loc;
    const int bm = (wgid / gx) * 256;
    const int bn = (wgid % gx) * 256;

    const int tid = threadIdx.x;
    const int lane = tid & 63;
    const int w = tid >> 6;
    const int wm = w >> 2;
    const int wn = w & 3;
    const int l15 = lane & 15;
    const int lk8 = (lane >> 4) * 8;
    const int swz = (l15 & 7) << 3;

    f32x4 acc[8][4];
#pragma unroll
    for (int i = 0; i < 8; ++i)
#pragma unroll
        for (int j = 0; j < 4; ++j)
#pragma unroll
            for (int r = 0; r < 4; ++r) acc[i][j][r] = 0.0f;

    const int srow = lane >> 3;
    const int scol = ((lane & 7) ^ srow) * 8;
    const bf16u* Ag[4];
    const bf16u* Wg[4];
    int loff[4];
#pragma unroll
    for (int p = 0; p < 4; ++p) {
        const int r = p * 64 + w * 8 + srow;
        Ag[p] = A + (long long)(bm + r) * lda + scol;
        Wg[p] = W + (long long)(bn + r) * K + scol;
        loff[p] = (p * 8 + w) * 512;
    }

    auto stage = [&](int kt, int b) {
        const long long k1 = (long long)kt << 6;
#pragma unroll
        for (int p = 0; p < 4; ++p) {
            __builtin_amdgcn_global_load_lds((const AS1 void*)(Ag[p] + k1),
                (AS3 void*)(&As[b][loff[p]]), 16, 0, 0);
            __builtin_amdgcn_global_load_lds((const AS1 void*)(Wg[p] + k1),
                (AS3 void*)(&Ws[b][loff[p]]), 16, 0, 0);
        }
    };
    auto compute = [&](int b) {
#pragma unroll
        for (int ks = 0; ks < 2; ++ks) {
            const int ko = (ks * 32 + lk8) ^ swz;
            short8v af[8], bfr[4];
#pragma unroll
            for (int i = 0; i < 8; ++i)
                af[i] = *(const short8v*)(&As[b][(wm * 128 + i * 16 + l15) * 64 + ko]);
#pragma unroll
            for (int i = 0; i < 4; ++i)
                bfr[i] = *(const short8v*)(&Ws[b][(wn * 64 + i * 16 + l15) * 64 + ko]);
#pragma unroll
            for (int mi = 0; mi < 8; ++mi)
#pragma unroll
                for (int ni = 0; ni < 4; ++ni)
                    acc[mi][ni] = __builtin_amdgcn_mfma_f32_16x16x32_bf16(
                        af[mi], bfr[ni], acc[mi][ni], 0, 0, 0);
        }
    };

    const int nt = K >> 6;

    stage(0, 0);
    stage(1, 1);

    for (int t = 0; t < nt - 1; ++t) {
        asm volatile("s_waitcnt vmcnt(8)" ::: "memory");
        __builtin_amdgcn_s_barrier();
        asm volatile("" ::: "memory");
        compute(t & 1);
        asm volatile("" ::: "memory");
        __builtin_amdgcn_s_barrier();
        if (t + 2 < nt) stage(t + 2, t & 1);
    }
    asm volatile("s_waitcnt vmcnt(0)" ::: "memory");
    __builtin_amdgcn_s_barrier();
    compute((nt - 1) & 1);

    const int r0 = (lane >> 4) * 4;
#pragma unroll
    for (int mi = 0; mi < 8; ++mi) {
#pragma unroll
        for (int ni = 0; ni < 4; ++ni) {
            const int col = bn + wn * 64 + ni * 16 + l15;
            float badd = bz ? bz[col] : 0.0f;
#pragma unroll
            for (int r = 0; r < 4; ++r) {
                const long long row = bm + wm * 128 + mi * 16 + r0 + r;
                float v = acc[mi][ni][r] + badd;
                if (act) v = tanhf(v);
                if constexpr (sizeof(TC) == 4) ((float*)C)[row * ldc + col] = v;
                else                           ((bf16u*)C)[row * ldc + col] = f2b(v);
            }
        }
    }
}

// ---------------------------------------------------------------------------
// 128x128 counted-vmcnt dbuf MFMA GEMM (4 waves, 64x64/wave), T2 swizzle,
// T5 setprio. For mid-size grids (P0P1, OC) that underfill at 256².
// ---------------------------------------------------------------------------
template <typename TC>
__global__ __launch_bounds__(256) void gemm_mfma128p(
    const bf16u* __restrict__ A, long long sAz, int lda,
    const bf16u* __restrict__ W, long long sWz,
    const float* __restrict__ bias, long long sBz,
    TC* __restrict__ C, long long sCz, int ldc,
    int K, int act)
{
    __shared__ bf16u As[2][128 * 64];
    __shared__ bf16u Ws[2][128 * 64];

    const int z = blockIdx.z;
    A += (long long)z * sAz;
    W += (long long)z * sWz;
    C += (long long)z * sCz;
    const float* bz = bias ? (bias + (long long)z * sBz) : nullptr;

    const int gx = gridDim.x;
    const int nwg = gx * gridDim.y;
    const int orig = blockIdx.y * gx + blockIdx.x;
    const int q = nwg >> 3, rres = nwg & 7;
    const int xcd = orig & 7, loc = orig >> 3;
    const int wgid = (xcd < rres ? xcd * (q + 1) : rres * (q + 1) + (xcd - rres) * q) + loc;
    const int bm = (wgid / gx) * 128;
    const int bn = (wgid % gx) * 128;

    const int tid = threadIdx.x;
    const int lane = tid & 63;
    const int w = tid >> 6;
    const int wm = w >> 1;
    const int wn = w & 1;
    const int l15 = lane & 15;
    const int lk8 = (lane >> 4) * 8;
    const int swz = (l15 & 7) << 3;

    f32x4 acc[4][4];
#pragma unroll
    for (int i = 0; i < 4; ++i)
#pragma unroll
        for (int j = 0; j < 4; ++j)
#pragma unroll
            for (int r = 0; r < 4; ++r) acc[i][j][r] = 0.0f;

    const int srow = lane >> 3;
    const int scol = ((lane & 7) ^ srow) * 8;
    const bf16u* Ag[4];
    const bf16u* Wg[4];
    int loff[4];
#pragma unroll
    for (int p = 0; p < 4; ++p) {
        const int r = p * 32 + w * 8 + srow;
        Ag[p] = A + (long long)(bm + r) * lda + scol;
        Wg[p] = W + (long long)(bn + r) * K + scol;
        loff[p] = (p * 32 + w * 8) * 64;
    }

    auto stage = [&](int kt, int b) {
        const long long k1 = (long long)kt << 6;
#pragma unroll
        for (int p = 0; p < 4; ++p) {
            __builtin_amdgcn_global_load_lds((const AS1 void*)(Ag[p] + k1),
                (AS3 void*)(&As[b][loff[p]]), 16, 0, 0);
            __builtin_amdgcn_global_load_lds((const AS1 void*)(Wg[p] + k1),
                (AS3 void*)(&Ws[b][loff[p]]), 16, 0, 0);
        }
    };
    auto compute = [&](int b) {
#pragma unroll
        for (int ks = 0; ks < 2; ++ks) {
            const int ko = (ks * 32 + lk8) ^ swz;
            short8v af[4], bfr[4];
#pragma unroll
            for (int i = 0; i < 4; ++i)
                af[i] = *(const short8v*)(&As[b][(wm * 64 + i * 16 + l15) * 64 + ko]);
#pragma unroll
            for (int i = 0; i < 4; ++i)
                bfr[i] = *(const short8v*)(&Ws[b][(wn * 64 + i * 16 + l15) * 64 + ko]);
            __builtin_amdgcn_s_setprio(1);
#pragma unroll
            for (int mi = 0; mi < 4; ++mi)
#pragma unroll
                for (int ni = 0; ni < 4; ++ni)
                    acc[mi][ni] = __builtin_amdgcn_mfma_f32_16x16x32_bf16(
                        af[mi], bfr[ni], acc[mi][ni], 0, 0, 0);
            __builtin_amdgcn_s_setprio(0);
        }
    };

    const int nt = K >> 6;

    stage(0, 0);
    stage(1, 1);

    for (int t = 0; t < nt - 1; ++t) {
        asm volatile("s_waitcnt vmcnt(8)" ::: "memory");
        __builtin_amdgcn_s_barrier();
        asm volatile("" ::: "memory");
        compute(t & 1);
        asm volatile("" ::: "memory");
        __builtin_amdgcn_s_barrier();
        if (t + 2 < nt) stage(t + 2, t & 1);
    }
    asm volatile("s_waitcnt vmcnt(0)" ::: "memory");
    __builtin_amdgcn_s_barrier();
    compute((nt - 1) & 1);

    const int r0 = (lane >> 4) * 4;
#pragma unroll
    for (int mi = 0; mi < 4; ++mi) {
#pragma unroll
        for (int ni = 0; ni < 4; ++ni) {
            const int col = bn + wn * 64 + ni * 16 + l15;
            float badd = bz ? bz[col] : 0.0f;
#pragma unroll
            for (int r = 0; r < 4; ++r) {
                const long long row = bm + wm * 64 + mi * 16 + r0 + r;
                float v = acc[mi][ni][r] + badd;
                if (act) v = tanhf(v);
                if constexpr (sizeof(TC) == 4) ((float*)C)[row * ldc + col] = v;
                else                           ((bf16u*)C)[row * ldc + col] = f2b(v);
            }
        }
    }
}

// ---------------------------------------------------------------------------
// 128x128 MFMA GEMM (R7-verified single-buffer; small dispatches only).
// ---------------------------------------------------------------------------
template <typename TC>
__global__ __launch_bounds__(256) void gemm_mfma(
    const bf16u* __restrict__ A, long long sAz, int lda,
    const bf16u* __restrict__ W, long long sWz,
    const float* __restrict__ bias, long long sBz,
    TC* __restrict__ C, long long sCz, int ldc,
    int K, int act)
{
    __shared__ bf16u As[128 * 64];
    __shared__ bf16u Ws[128 * 64];

    const int z = blockIdx.z;
    A += (long long)z * sAz;
    W += (long long)z * sWz;
    C += (long long)z * sCz;
    const float* bz = bias ? (bias + (long long)z * sBz) : nullptr;

    const int gx = gridDim.x;
    const int nwg = gx * gridDim.y;
    const int orig = blockIdx.y * gx + blockIdx.x;
    const int q = nwg >> 3, rres = nwg & 7;
    const int xcd = orig & 7, loc = orig >> 3;
    const int wgid = (xcd < rres ? xcd * (q + 1) : rres * (q + 1) + (xcd - rres) * q) + loc;
    const int bm = (wgid / gx) * 128;
    const int bn = (wgid % gx) * 128;

    const int tid = threadIdx.x;
    const int lane = tid & 63;
    const int wave = tid >> 6;
    const int wr = (wave >> 1) * 64;
    const int wc = (wave & 1) * 64;
    const int l15 = lane & 15;
    const int lk8 = (lane >> 4) * 8;

    f32x4 acc[4][4];
#pragma unroll
    for (int i = 0; i < 4; ++i)
#pragma unroll
        for (int j = 0; j < 4; ++j)
#pragma unroll
            for (int r = 0; r < 4; ++r) acc[i][j][r] = 0.0f;

    const int sr = wave * 32 + (lane >> 3);
    const int sc = (lane & 7) * 8;
    const bf16u* Ag = A + (long long)(bm + sr) * lda + sc;
    const bf16u* Wg = W + (long long)(bn + sr) * K + sc;
    bf16u* Al = As + wave * 32 * 64;
    bf16u* Wl = Ws + wave * 32 * 64;

    for (int k0 = 0; k0 < K; k0 += 64) {
#pragma unroll
        for (int p = 0; p < 4; ++p) {
            __builtin_amdgcn_global_load_lds(
                (const AS1 void*)(Ag + k0 + (long long)(8 * p) * lda),
                (AS3 void*)(Al + 8 * p * 64), 16, 0, 0);
            __builtin_amdgcn_global_load_lds(
                (const AS1 void*)(Wg + k0 + (long long)(8 * p) * K),
                (AS3 void*)(Wl + 8 * p * 64), 16, 0, 0);
        }
        __syncthreads();
#pragma unroll
        for (int ks = 0; ks < 2; ++ks) {
            short8v af[4], bfr[4];
#pragma unroll
            for (int i = 0; i < 4; ++i)
                af[i] = *(const short8v*)(As + (wr + i * 16 + l15) * 64 + ks * 32 + lk8);
#pragma unroll
            for (int i = 0; i < 4; ++i)
                bfr[i] = *(const short8v*)(Ws + (wc + i * 16 + l15) * 64 + ks * 32 + lk8);
#pragma unroll
            for (int mi = 0; mi < 4; ++mi)
#pragma unroll
                for (int ni = 0; ni < 4; ++ni)
                    acc[mi][ni] = __builtin_amdgcn_mfma_f32_16x16x32_bf16(
                        af[mi], bfr[ni], acc[mi][ni], 0, 0, 0);
        }
        __syncthreads();
    }

    const int r0 = (lane >> 4) * 4;
#pragma unroll
    for (int mi = 0; mi < 4; ++mi) {
#pragma unroll
        for (int ni = 0; ni < 4; ++ni) {
            const int col = bn + wc + ni * 16 + l15;
            float badd = bz ? bz[col] : 0.0f;
#pragma unroll
            for (int r = 0; r < 4; ++r) {
                const long long row = bm + wr + mi * 16 + r0 + r;
                float v = acc[mi][ni][r] + badd;
                if (act) v = tanhf(v);
                if constexpr (sizeof(TC) == 4) ((float*)C)[row * ldc + col] = v;
                else                           ((bf16u*)C)[row * ldc + col] = f2b(v);
            }
        }
    }
}

// ---------------------------------------------------------------------------
// FUSED GRU step (R14/15 verified: counted-vmcnt dbuf + T2 swizzle + setprio).
// 64M x 32N x 3 gates, BK=64, 8 K-tiles, LDS 40KB -> 4 blocks/CU.
// ---------------------------------------------------------------------------
template <int LAYER, bool FIRST>
__global__ __launch_bounds__(256) void gru_step(
    const bf16u* __restrict__ Hb,
    const bf16u* __restrict__ Whh,
    const float* __restrict__ bhh,
    const bf16u* __restrict__ P0,
    const bf16u* __restrict__ P1,
    const float* __restrict__ bih,
    const bf16u* __restrict__ GIT,
    const float* __restrict__ hprev,
    float* __restrict__ hnext,
    bf16u* __restrict__ hnextb,
    bf16u* __restrict__ hout,
    int t, int CB)
{
    __shared__ bf16u As[2][64 * 64];
    __shared__ bf16u Ws[2][96 * 64];

    const int z = blockIdx.z;
    const int bn = blockIdx.x * 32;
    const int bm = blockIdx.y * 64;
    const int tid = threadIdx.x;
    const int lane = tid & 63;
    const int wave = tid >> 6;
    const int wm = wave >> 1;
    const int wn = wave & 1;
    const int l15 = lane & 15;
    const int lk8 = (lane >> 4) * 8;
    const int swz = (l15 & 7) << 3;

    f32x4 acc[3][2];
#pragma unroll
    for (int g = 0; g < 3; ++g)
#pragma unroll
        for (int i = 0; i < 2; ++i)
#pragma unroll
            for (int r = 0; r < 4; ++r) acc[g][i][r] = 0.0f;

    if constexpr (!FIRST) {
        const bf16u* hsrc = Hb + (long long)z * CB * 512;
        const bf16u* wsrc = Whh + (long long)z * 1536 * 512;

        const int srow = lane >> 3;
        const int sc = ((lane & 7) ^ srow) * 8;
        const bf16u* Ag = hsrc + (long long)(bm + 16 * wave + srow) * 512 + sc;
        const bf16u* Wg[3];
#pragma unroll
        for (int p = 0; p < 3; ++p) {
            const int lr = 24 * wave + 8 * p + srow;
            const int g = lr >> 5, c = lr & 31;
            Wg[p] = wsrc + (long long)(g * 512 + bn + c) * 512 + sc;
        }

        auto stage = [&](int kt, int b) {
            const long long k0 = (long long)kt << 6;
#pragma unroll
            for (int p = 0; p < 2; ++p)
                __builtin_amdgcn_global_load_lds(
                    (const AS1 void*)(Ag + k0 + (long long)(8 * p) * 512),
                    (AS3 void*)(&As[b][(16 * wave + 8 * p) * 64]), 16, 0, 0);
#pragma unroll
            for (int p = 0; p < 3; ++p)
                __builtin_amdgcn_global_load_lds(
                    (const AS1 void*)(Wg[p] + k0),
                    (AS3 void*)(&Ws[b][(24 * wave + 8 * p) * 64]), 16, 0, 0);
        };
        auto compute = [&](int b) {
#pragma unroll
            for (int ks = 0; ks < 2; ++ks) {
                const int ko = (ks * 32 + lk8) ^ swz;
                short8v af[2], bf[3];
#pragma unroll
                for (int mi = 0; mi < 2; ++mi)
                    af[mi] = *(const short8v*)(&As[b][(wm * 32 + mi * 16 + l15) * 64 + ko]);
#pragma unroll
                for (int g = 0; g < 3; ++g)
                    bf[g] = *(const short8v*)(&Ws[b][(g * 32 + wn * 16 + l15) * 64 + ko]);
                __builtin_amdgcn_s_setprio(1);
#pragma unroll
                for (int g = 0; g < 3; ++g)
#pragma unroll
                    for (int mi = 0; mi < 2; ++mi)
                        acc[g][mi] = __builtin_amdgcn_mfma_f32_16x16x32_bf16(
                            af[mi], bf[g], acc[g][mi], 0, 0, 0);
                __builtin_amdgcn_s_setprio(0);
            }
        };

        stage(0, 0);
        stage(1, 1);
        for (int kt = 0; kt < 7; ++kt) {
            asm volatile("s_waitcnt vmcnt(5)" ::: "memory");
            __builtin_amdgcn_s_barrier();
            asm volatile("" ::: "memory");
            compute(kt & 1);
            asm volatile("" ::: "memory");
            __builtin_amdgcn_s_barrier();
            if (kt + 2 < 8) stage(kt + 2, kt & 1);
        }
        asm volatile("s_waitcnt vmcnt(0)" ::: "memory");
        __builtin_amdgcn_s_barrier();
        compute(1);
    }

    const int r0 = (lane >> 4) * 4;
    const int s = z ? (SEQ - 1 - t) : t;
    float c0 = 0.0f, c1 = 0.0f;
    if (LAYER == 0) {
        float ph = 0.6283185307179586f * (float)s;
        c0 = 1.0f + 0.1f * cosf(ph);
        c1 = 0.05f * sinf(ph);
    }

    const int j = bn + wn * 16 + l15;
    const float bh0 = bhh[z * 1536 + j];
    const float bh1 = bhh[z * 1536 + 512 + j];
    const float bh2 = bhh[z * 1536 + 1024 + j];
    float bi0 = 0, bi1 = 0, bi2 = 0;
    if (LAYER == 0) {
        bi0 = bih[z * 1536 + j];
        bi1 = bih[z * 1536 + 512 + j];
        bi2 = bih[z * 1536 + 1024 + j];
    }

#pragma unroll
    for (int mi = 0; mi < 2; ++mi) {
#pragma unroll
        for (int rr = 0; rr < 4; ++rr) {
            const int m = bm + wm * 32 + mi * 16 + r0 + rr;
            float gr = acc[0][mi][rr] + bh0;
            float gz = acc[1][mi][rr] + bh1;
            float gn = acc[2][mi][rr] + bh2;
            float ir, iz, inn;
            if (LAYER == 0) {
                const bf16u* p0 = P0 + (long long)m * 3072 + z * 1536 + j;
                const bf16u* p1 = P1 + (long long)m * 3072 + z * 1536 + j;
                ir  = c0 * b2f(p0[0])    + c1 * b2f(p1[0])    + bi0;
                iz  = c0 * b2f(p0[512])  + c1 * b2f(p1[512])  + bi1;
                inn = c0 * b2f(p0[1024]) + c1 * b2f(p1[1024]) + bi2;
            } else {
                const bf16u* gi = GIT + (((long long)z * CB + m) * SEQ + s) * 1536 + j;
                ir = b2f(gi[0]); iz = b2f(gi[512]); inn = b2f(gi[1024]);
            }
            const long long ho = ((long long)z * CB + m) * 512 + j;
            float r  = fast_sigm(ir + gr);
            float zz = fast_sigm(iz + gz);
            float n  = fast_tanh(inn + r * gn);
            float hnew;
            if constexpr (FIRST) hnew = (1.0f - zz) * n;
            else                 hnew = (1.0f - zz) * n + zz * hprev[ho];
            hnext[ho]  = hnew;
            hnextb[ho] = f2b(hnew);
            hout[((long long)m * SEQ + s) * 1024 + z * 512 + j] = f2b(hnew);
        }
    }
}

__global__ void roll_b(const bf16u* __restrict__ xp, bf16u* __restrict__ rl)
{
    int idx = blockIdx.x * 256 + threadIdx.x;
    int i = idx & 511;
    int b = idx >> 9;
    rl[(size_t)b * 512 + i] = xp[(size_t)b * 512 + ((i + 511) & 511)];
}

// fused attention per (b_local, head): SEQ=10, HD=128; fp32 math, bf16 I/O
__global__ __launch_bounds__(128) void attn_kernel(const bf16u* __restrict__ qkv,
                                                   bf16u* __restrict__ o)
{
    const int bh = blockIdx.x;
    const int h = bh & 7;
    const int bl = bh >> 3;
    const int tid = threadIdx.x;

    __shared__ float Q[SEQ][128], Kx[SEQ][128], V[SEQ][128], Amat[SEQ][SEQ];

    const bf16u* base = qkv + (size_t)bl * SEQ * 3072 + h * 128;
#pragma unroll
    for (int s = 0; s < SEQ; ++s) {
        Q[s][tid]  = b2f(base[s * 3072 + tid]);
        Kx[s][tid] = b2f(base[s * 3072 + 1024 + tid]);
        V[s][tid]  = b2f(base[s * 3072 + 2048 + tid]);
    }
    __syncthreads();

    if (tid < SEQ * SEQ) {
        int q = tid / SEQ, k = tid % SEQ;
        float acc = 0.0f;
#pragma unroll 8
        for (int d0 = 0; d0 < 128; ++d0) acc += Q[q][d0] * Kx[k][d0];
        Amat[q][k] = acc * 0.08838834764831845f;
    }
    __syncthreads();

    if (tid < SEQ) {
        float m = -1e30f;
#pragma unroll
        for (int k = 0; k < SEQ; ++k) m = fmaxf(m, Amat[tid][k]);
        float e[SEQ], ssum = 0.0f;
#pragma unroll
        for (int k = 0; k < SEQ; ++k) { e[k] = expf(Amat[tid][k] - m); ssum += e[k]; }
        float inv = 1.0f / ssum;
#pragma unroll
        for (int k = 0; k < SEQ; ++k) Amat[tid][k] = e[k] * inv;
    }
    __syncthreads();

    bf16u* ob = o + (size_t)bl * SEQ * 1024 + h * 128;
#pragma unroll
    for (int q = 0; q < SEQ; ++q) {
        float acc = 0.0f;
#pragma unroll
        for (int k = 0; k < SEQ; ++k) acc += Amat[q][k] * V[k][tid];
        ob[q * 1024 + tid] = f2b(acc);
    }
}

// agg[b][j] = 0.1 * sum_s (go[b][s][j] + ao[b][s][j]); 4 el/thread, bf16 out
__global__ void mean_kernel(const bf16u* __restrict__ go, const bf16u* __restrict__ ao,
                            bf16u* __restrict__ agg)
{
    int idx = blockIdx.x * 256 + threadIdx.x;
    int j4 = (idx & 255) * 4;
    int bl = idx >> 8;
    const bf16u* g = go + (size_t)bl * (SEQ * 1024) + j4;
    const bf16u* a = ao + (size_t)bl * (SEQ * 1024) + j4;
    float s0 = 0, s1 = 0, s2 = 0, s3 = 0;
#pragma unroll
    for (int t = 0; t < SEQ; ++t) {
        ushort4 gv = *(const ushort4*)(g + t * 1024);
        ushort4 av = *(const ushort4*)(a + t * 1024);
        s0 += b2f(gv.x) + b2f(av.x);
        s1 += b2f(gv.y) + b2f(av.y);
        s2 += b2f(gv.z) + b2f(av.z);
        s3 += b2f(gv.w) + b2f(av.w);
    }
    ushort4 u; u.x = f2b(0.1f * s0); u.y = f2b(0.1f * s1); u.z = f2b(0.1f * s2); u.w = f2b(0.1f * s3);
    *(ushort4*)(agg + (size_t)bl * 1024 + j4) = u;
}

extern "C" void kernel_launch(void* const* d_in, const int* in_sizes, int n_in,
                              void* d_out, int out_size, void* d_ws, size_t ws_size,
                              hipStream_t stream)
{
    const float* x    = (const float*)d_in[0];
    const float* Wp   = (const float*)d_in[1];
    const float* bp   = (const float*)d_in[2];
    const float* Wih0 = (const float*)d_in[3];
    const float* Whh0 = (const float*)d_in[4];
    const float* bih0 = (const float*)d_in[5];
    const float* bhh0 = (const float*)d_in[6];
    const float* Wih1 = (const float*)d_in[7];
    const float* Whh1 = (const float*)d_in[8];
    const float* bih1 = (const float*)d_in[9];
    const float* bhh1 = (const float*)d_in[10];
    const float* ipw  = (const float*)d_in[11];
    const float* ipb  = (const float*)d_in[12];
    const float* opw  = (const float*)d_in[13];
    const float* opb  = (const float*)d_in[14];
    const float* W1   = (const float*)d_in[15];
    const float* b1   = (const float*)d_in[16];
    const float* W2   = (const float*)d_in[17];
    const float* b2   = (const float*)d_in[18];
    float* out = (float*)d_out;

    const long long WOVER = 9437184LL;
    const long long WALL  = 24969216LL;
    int CB = 0;
    for (int c = 4096; c >= 128; c >>= 1)
        if (WOVER + (long long)c * 114688 <= (long long)ws_size) { CB = c; break; }
    if (CB == 0) return;
    const bool resident = (WALL + (long long)CB * 114688 <= (long long)ws_size);
    const long long WB = resident ? WALL : WOVER;
    const int CBA = CB / 2;

    bf16u* wreg = (bf16u*)d_ws;
    bf16u *Wpb, *Wih0b, *Whh0b, *Wih1b, *Whh1b, *ipwb, *opwb, *W1b, *W2b;
    if (resident) {
        Wpb   = wreg;
        Wih0b = wreg + 262144;
        Whh0b = wreg + 1835008;
        Wih1b = wreg + 3407872;
        Whh1b = wreg + 6553600;
        ipwb  = wreg + 8126464;
        opwb  = wreg + 11272192;
        W1b   = wreg + 12320768;
        W2b   = wreg + 12451840;
    } else {
        Wpb   = wreg;
        Wih0b = wreg + 262144;
        Whh0b = wreg + 1835008;
        Wih1b = wreg;
        Whh1b = wreg + 3145728;
        ipwb  = wreg;
        opwb  = wreg + 3145728;
        W1b   = wreg + 4194304;
        W2b   = wreg + 4325376;
    }

    char* A0 = (char*)d_ws + WB;
    bf16u* H1c = (bf16u*)A0;
    bf16u* GOc = (bf16u*)(A0 + 20480LL * CB);
    char*  U   = A0 + 40960LL * CB;
    bf16u* P0    = (bf16u*)U;
    bf16u* P1    = (bf16u*)(U + 6144LL * CB);
    bf16u* XB    = (bf16u*)(U + 12288LL * CB);
    bf16u* XPb   = (bf16u*)(U + 13312LL * CB);
    bf16u* RLb   = (bf16u*)(U + 14336LL * CB);
    bf16u* GIT   = (bf16u*)U;
    char*  HC    = U + 61440LL * CB;
    bf16u* QKV   = (bf16u*)U;
    bf16u* OC    = (bf16u*)(U + 61440LL * CB);
    bf16u* AOC   = (bf16u*)A0;
    bf16u* AGGb  = (bf16u*)(A0 + 10240LL * CB);
    bf16u* HIDb  = (bf16u*)(A0 + 12288LL * CB);

    const dim3 blk(256);
    const int MB = CB / 128;

    auto cvt = [&](const float* s, bf16u* d, long long nfloats) {
        int n4 = (int)(nfloats / 4);
        cvt_f2b<<<(n4 + 255) / 256, blk, 0, stream>>>(s, d, n4);
    };

    if (resident) {
        cvt(Wp,   Wpb,   512LL * 512);
        cvt(Wih0, Wih0b, 2LL * 1536 * 512);
        cvt(Whh0, Whh0b, 2LL * 1536 * 512);
        cvt(Wih1, Wih1b, 2LL * 1536 * 1024);
        cvt(Whh1, Whh1b, 2LL * 1536 * 512);
        cvt(ipw,  ipwb,  3072LL * 1024);
        cvt(opw,  opwb,  1024LL * 1024);
        cvt(W1,   W1b,   128LL * 1024);
        cvt(W2,   W2b,   256LL * 128);
    }

    for (int c0 = 0; c0 < 4096; c0 += CB) {
        // ---------------- phase A: preproc + layer-0 biGRU ----------------
        cvt(x + (long long)c0 * 512, XB, (long long)CB * 512);
        if (!resident) {
            cvt(Wp,   Wpb,   512LL * 512);
            cvt(Wih0, Wih0b, 2LL * 1536 * 512);
            cvt(Whh0, Whh0b, 2LL * 1536 * 512);
        }

        gemm_mfma<bf16u><<<dim3(4, MB, 1), blk, 0, stream>>>(
            XB, 0, 512, Wpb, 0, bp, 0, XPb, 0, 512, 512, 0);
        roll_b<<<CB * 2, blk, 0, stream>>>(XPb, RLb);
        gemm_mfma128p<bf16u><<<dim3(24, MB, 2), blk, 0, stream>>>(
            XPb, (long long)CB * 512, 512, Wih0b, 0, nullptr, 0,
            P0, (long long)CB * 3072, 3072, 512, 0);

        for (int t = 0; t < SEQ; ++t) {
            const int rb = t & 1;
            float* hprev  = (float*)(HC + (long long)rb * 6144 * CB);
            bf16u* Hbr    = (bf16u*)(HC + (long long)rb * 6144 * CB + 4096LL * CB);
            float* hnext  = (float*)(HC + (long long)(1 - rb) * 6144 * CB);
            bf16u* hnextb = (bf16u*)(HC + (long long)(1 - rb) * 6144 * CB + 4096LL * CB);
            if (t == 0)
                gru_step<0, true><<<dim3(16, CB / 64, 2), blk, 0, stream>>>(
                    Hbr, Whh0b, bhh0, P0, P1, bih0, nullptr,
                    hprev, hnext, hnextb, H1c, t, CB);
            else
                gru_step<0, false><<<dim3(16, CB / 64, 2), blk, 0, stream>>>(
                    Hbr, Whh0b, bhh0, P0, P1, bih0, nullptr,
                    hprev, hnext, hnextb, H1c, t, CB);
        }

        // ---------------- phase B: layer-1 biGRU ----------------
        if (!resident) {
            cvt(Wih1, Wih1b, 2LL * 1536 * 1024);
            cvt(Whh1, Whh1b, 2LL * 1536 * 512);
        }
        gemm_mfma256<bf16u><<<dim3(6, CB * 10 / 256, 2), dim3(512), 0, stream>>>(
            H1c, 0, 1024, Wih1b, 1536LL * 1024, bih1, 1536,
            GIT, (long long)CB * SEQ * 1536, 1536, 1024, 0);

        for (int t = 0; t < SEQ; ++t) {
            const int rb = t & 1;
            float* hprev  = (float*)(HC + (long long)rb * 6144 * CB);
            bf16u* Hbr    = (bf16u*)(HC + (long long)rb * 6144 * CB + 4096LL * CB);
            float* hnext  = (float*)(HC + (long long)(1 - rb) * 6144 * CB);
            bf16u* hnextb = (bf16u*)(HC + (long long)(1 - rb) * 6144 * CB + 4096LL * CB);
            if (t == 0)
                gru_step<1, true><<<dim3(16, CB / 64, 2), blk, 0, stream>>>(
                    Hbr, Whh1b, bhh1, nullptr, nullptr, nullptr, GIT,
                    hprev, hnext, hnextb, GOc, t, CB);
            else
                gru_step<1, false><<<dim3(16, CB / 64, 2), blk, 0, stream>>>(
                    Hbr, Whh1b, bhh1, nullptr, nullptr, nullptr, GIT,
                    hprev, hnext, hnextb, GOc, t, CB);
        }

        // ---------------- phase C: attention + head ----------------
        if (!resident) {
            cvt(ipw, ipwb, 3072LL * 1024);
            cvt(opw, opwb, 1024LL * 1024);
            cvt(W1,  W1b,  128LL * 1024);
            cvt(W2,  W2b,  256LL * 128);
        }
        gemm_mfma256<bf16u><<<dim3(12, CB * 10 / 256, 1), dim3(512), 0, stream>>>(
            GOc, 0, 1024, ipwb, 0, ipb, 0, QKV, 0, 3072, 1024, 0);
        for (int a0 = 0; a0 < CB; a0 += CBA) {
            attn_kernel<<<CBA * 8, dim3(128), 0, stream>>>(
                QKV + (long long)a0 * 30720, OC);
            gemm_mfma128p<bf16u><<<dim3(8, CBA * 10 / 128, 1), blk, 0, stream>>>(
                OC, 0, 1024, opwb, 0, opb, 0, AOC, 0, 1024, 1024, 0);
            mean_kernel<<<CBA, blk, 0, stream>>>(
                GOc + (long long)a0 * 10240, AOC, AGGb + (long long)a0 * 1024);
        }
        gemm_mfma<bf16u><<<dim3(1, MB, 1), blk, 0, stream>>>(
            AGGb, 0, 1024, W1b, 0, b1, 0, HIDb, 0, 128, 1024, 1);
        gemm_mfma<float><<<dim3(2, MB, 1), blk, 0, stream>>>(
            HIDb, 0, 128, W2b, 0, b2, 0, out + (long long)c0 * 256, 0, 256, 128, 0);
    }
}

// Round 17
// 2025.458 us; speedup vs baseline: 1.0836x; 1.0482x over previous
//
#include <hip/hip_runtime.h>
#include <math.h>

// ---------------------------------------------------------------------------
// GRUFeatureExtractor — bf16 MFMA everywhere, fused GRU steps.
//   R17: ALGEBRAIC out-proj reduction. mean_s(o@opw^T+opb) = 0.1*(sum_s o)
//   @opw^T + opb  ->  attention kernel accumulates sum_s o in-register and
//   writes ONE 1024-vec per row (OSUM); out-proj GEMM shrinks M=CB*10 ->
//   M=CB (10x fewer FLOPs, no OC/AOC round-trips, 12->3 launches/chunk).
//   All GEMM/GRU kernels byte-identical to R16 (2,123us verified).
// ---------------------------------------------------------------------------

#define SEQ 10

typedef unsigned short bf16u;
typedef __attribute__((ext_vector_type(8))) short short8v;   // 8 bf16
typedef __attribute__((ext_vector_type(4))) float f32x4;     // MFMA C/D

#define AS1 __attribute__((address_space(1)))
#define AS3 __attribute__((address_space(3)))

__device__ __forceinline__ float b2f(bf16u u) {
    union { unsigned int i; float f; } v; v.i = ((unsigned int)u) << 16; return v.f;
}
__device__ __forceinline__ bf16u f2b(float f) {
    union { float f; unsigned int i; } v; v.f = f;
    unsigned int r = (v.i + 0x7FFFu + ((v.i >> 16) & 1u)) >> 16;
    return (bf16u)r;
}
__device__ __forceinline__ float fast_sigm(float x) { return 1.0f / (1.0f + __expf(-x)); }
__device__ __forceinline__ float fast_tanh(float x) {
    float e = __expf(-2.0f * x);
    return 2.0f / (1.0f + e) - 1.0f;
}

__global__ void cvt_f2b(const float* __restrict__ src, bf16u* __restrict__ dst, int n4)
{
    int i = blockIdx.x * 256 + threadIdx.x;
    if (i < n4) {
        float4 v = ((const float4*)src)[i];
        ushort4 u; u.x = f2b(v.x); u.y = f2b(v.y); u.z = f2b(v.z); u.w = f2b(v.w);
        ((ushort4*)dst)[i] = u;
    }
}

// ---------------------------------------------------------------------------
// 256x256 counted-vmcnt double-buffered MFMA GEMM (8 waves, 128x64/wave),
// T2 swizzle. R14/R16-verified: 207us, 0 bank conflicts. LDS 128KB.
// ---------------------------------------------------------------------------
template <typename TC>
__global__ __launch_bounds__(512) void gemm_mfma256(
    const bf16u* __restrict__ A, long long sAz, int lda,
    const bf16u* __restrict__ W, long long sWz,
    const float* __restrict__ bias, long long sBz,
    TC* __restrict__ C, long long sCz, int ldc,
    int K, int act)
{
    __shared__ bf16u As[2][256 * 64];
    __shared__ bf16u Ws[2][256 * 64];

    const int z = blockIdx.z;
    A += (long long)z * sAz;
    W += (long long)z * sWz;
    C += (long long)z * sCz;
    const float* bz = bias ? (bias + (long long)z * sBz) : nullptr;

    const int gx = gridDim.x;
    const int nwg = gx * gridDim.y;
    const int orig = blockIdx.y * gx + blockIdx.x;
    const int q = nwg >> 3, rres = nwg & 7;
    const int xcd = orig & 7, loc = orig >> 3;
    const int wgid = (xcd < rres ? xcd * (q + 1) : rres * (q + 1) + (xcd - rres) * q) + loc;
    const int bm = (wgid / gx) * 256;
    const int bn = (wgid % gx) * 256;

    const int tid = threadIdx.x;
    const int lane = tid & 63;
    const int w = tid >> 6;
    const int wm = w >> 2;
    const int wn = w & 3;
    const int l15 = lane & 15;
    const int lk8 = (lane >> 4) * 8;
    const int swz = (l15 & 7) << 3;

    f32x4 acc[8][4];
#pragma unroll
    for (int i = 0; i < 8; ++i)
#pragma unroll
        for (int j = 0; j < 4; ++j)
#pragma unroll
            for (int r = 0; r < 4; ++r) acc[i][j][r] = 0.0f;

    const int srow = lane >> 3;
    const int scol = ((lane & 7) ^ srow) * 8;
    const bf16u* Ag[4];
    const bf16u* Wg[4];
    int loff[4];
#pragma unroll
    for (int p = 0; p < 4; ++p) {
        const int r = p * 64 + w * 8 + srow;
        Ag[p] = A + (long long)(bm + r) * lda + scol;
        Wg[p] = W + (long long)(bn + r) * K + scol;
        loff[p] = (p * 8 + w) * 512;
    }

    auto stage = [&](int kt, int b) {
        const long long k1 = (long long)kt << 6;
#pragma unroll
        for (int p = 0; p < 4; ++p) {
            __builtin_amdgcn_global_load_lds((const AS1 void*)(Ag[p] + k1),
                (AS3 void*)(&As[b][loff[p]]), 16, 0, 0);
            __builtin_amdgcn_global_load_lds((const AS1 void*)(Wg[p] + k1),
                (AS3 void*)(&Ws[b][loff[p]]), 16, 0, 0);
        }
    };
    auto compute = [&](int b) {
#pragma unroll
        for (int ks = 0; ks < 2; ++ks) {
            const int ko = (ks * 32 + lk8) ^ swz;
            short8v af[8], bfr[4];
#pragma unroll
            for (int i = 0; i < 8; ++i)
                af[i] = *(const short8v*)(&As[b][(wm * 128 + i * 16 + l15) * 64 + ko]);
#pragma unroll
            for (int i = 0; i < 4; ++i)
                bfr[i] = *(const short8v*)(&Ws[b][(wn * 64 + i * 16 + l15) * 64 + ko]);
#pragma unroll
            for (int mi = 0; mi < 8; ++mi)
#pragma unroll
                for (int ni = 0; ni < 4; ++ni)
                    acc[mi][ni] = __builtin_amdgcn_mfma_f32_16x16x32_bf16(
                        af[mi], bfr[ni], acc[mi][ni], 0, 0, 0);
        }
    };

    const int nt = K >> 6;

    stage(0, 0);
    stage(1, 1);

    for (int t = 0; t < nt - 1; ++t) {
        asm volatile("s_waitcnt vmcnt(8)" ::: "memory");
        __builtin_amdgcn_s_barrier();
        asm volatile("" ::: "memory");
        compute(t & 1);
        asm volatile("" ::: "memory");
        __builtin_amdgcn_s_barrier();
        if (t + 2 < nt) stage(t + 2, t & 1);
    }
    asm volatile("s_waitcnt vmcnt(0)" ::: "memory");
    __builtin_amdgcn_s_barrier();
    compute((nt - 1) & 1);

    const int r0 = (lane >> 4) * 4;
#pragma unroll
    for (int mi = 0; mi < 8; ++mi) {
#pragma unroll
        for (int ni = 0; ni < 4; ++ni) {
            const int col = bn + wn * 64 + ni * 16 + l15;
            float badd = bz ? bz[col] : 0.0f;
#pragma unroll
            for (int r = 0; r < 4; ++r) {
                const long long row = bm + wm * 128 + mi * 16 + r0 + r;
                float v = acc[mi][ni][r] + badd;
                if (act) v = tanhf(v);
                if constexpr (sizeof(TC) == 4) ((float*)C)[row * ldc + col] = v;
                else                           ((bf16u*)C)[row * ldc + col] = f2b(v);
            }
        }
    }
}

// ---------------------------------------------------------------------------
// 128x128 counted-vmcnt dbuf MFMA GEMM (4 waves, 64x64/wave), T2 swizzle,
// T5 setprio. For mid-size grids (P0P1, out-proj) that underfill at 256².
// ---------------------------------------------------------------------------
template <typename TC>
__global__ __launch_bounds__(256) void gemm_mfma128p(
    const bf16u* __restrict__ A, long long sAz, int lda,
    const bf16u* __restrict__ W, long long sWz,
    const float* __restrict__ bias, long long sBz,
    TC* __restrict__ C, long long sCz, int ldc,
    int K, int act)
{
    __shared__ bf16u As[2][128 * 64];
    __shared__ bf16u Ws[2][128 * 64];

    const int z = blockIdx.z;
    A += (long long)z * sAz;
    W += (long long)z * sWz;
    C += (long long)z * sCz;
    const float* bz = bias ? (bias + (long long)z * sBz) : nullptr;

    const int gx = gridDim.x;
    const int nwg = gx * gridDim.y;
    const int orig = blockIdx.y * gx + blockIdx.x;
    const int q = nwg >> 3, rres = nwg & 7;
    const int xcd = orig & 7, loc = orig >> 3;
    const int wgid = (xcd < rres ? xcd * (q + 1) : rres * (q + 1) + (xcd - rres) * q) + loc;
    const int bm = (wgid / gx) * 128;
    const int bn = (wgid % gx) * 128;

    const int tid = threadIdx.x;
    const int lane = tid & 63;
    const int w = tid >> 6;
    const int wm = w >> 1;
    const int wn = w & 1;
    const int l15 = lane & 15;
    const int lk8 = (lane >> 4) * 8;
    const int swz = (l15 & 7) << 3;

    f32x4 acc[4][4];
#pragma unroll
    for (int i = 0; i < 4; ++i)
#pragma unroll
        for (int j = 0; j < 4; ++j)
#pragma unroll
            for (int r = 0; r < 4; ++r) acc[i][j][r] = 0.0f;

    const int srow = lane >> 3;
    const int scol = ((lane & 7) ^ srow) * 8;
    const bf16u* Ag[4];
    const bf16u* Wg[4];
    int loff[4];
#pragma unroll
    for (int p = 0; p < 4; ++p) {
        const int r = p * 32 + w * 8 + srow;
        Ag[p] = A + (long long)(bm + r) * lda + scol;
        Wg[p] = W + (long long)(bn + r) * K + scol;
        loff[p] = (p * 32 + w * 8) * 64;
    }

    auto stage = [&](int kt, int b) {
        const long long k1 = (long long)kt << 6;
#pragma unroll
        for (int p = 0; p < 4; ++p) {
            __builtin_amdgcn_global_load_lds((const AS1 void*)(Ag[p] + k1),
                (AS3 void*)(&As[b][loff[p]]), 16, 0, 0);
            __builtin_amdgcn_global_load_lds((const AS1 void*)(Wg[p] + k1),
                (AS3 void*)(&Ws[b][loff[p]]), 16, 0, 0);
        }
    };
    auto compute = [&](int b) {
#pragma unroll
        for (int ks = 0; ks < 2; ++ks) {
            const int ko = (ks * 32 + lk8) ^ swz;
            short8v af[4], bfr[4];
#pragma unroll
            for (int i = 0; i < 4; ++i)
                af[i] = *(const short8v*)(&As[b][(wm * 64 + i * 16 + l15) * 64 + ko]);
#pragma unroll
            for (int i = 0; i < 4; ++i)
                bfr[i] = *(const short8v*)(&Ws[b][(wn * 64 + i * 16 + l15) * 64 + ko]);
            __builtin_amdgcn_s_setprio(1);
#pragma unroll
            for (int mi = 0; mi < 4; ++mi)
#pragma unroll
                for (int ni = 0; ni < 4; ++ni)
                    acc[mi][ni] = __builtin_amdgcn_mfma_f32_16x16x32_bf16(
                        af[mi], bfr[ni], acc[mi][ni], 0, 0, 0);
            __builtin_amdgcn_s_setprio(0);
        }
    };

    const int nt = K >> 6;

    stage(0, 0);
    stage(1, 1);

    for (int t = 0; t < nt - 1; ++t) {
        asm volatile("s_waitcnt vmcnt(8)" ::: "memory");
        __builtin_amdgcn_s_barrier();
        asm volatile("" ::: "memory");
        compute(t & 1);
        asm volatile("" ::: "memory");
        __builtin_amdgcn_s_barrier();
        if (t + 2 < nt) stage(t + 2, t & 1);
    }
    asm volatile("s_waitcnt vmcnt(0)" ::: "memory");
    __builtin_amdgcn_s_barrier();
    compute((nt - 1) & 1);

    const int r0 = (lane >> 4) * 4;
#pragma unroll
    for (int mi = 0; mi < 4; ++mi) {
#pragma unroll
        for (int ni = 0; ni < 4; ++ni) {
            const int col = bn + wn * 64 + ni * 16 + l15;
            float badd = bz ? bz[col] : 0.0f;
#pragma unroll
            for (int r = 0; r < 4; ++r) {
                const long long row = bm + wm * 64 + mi * 16 + r0 + r;
                float v = acc[mi][ni][r] + badd;
                if (act) v = tanhf(v);
                if constexpr (sizeof(TC) == 4) ((float*)C)[row * ldc + col] = v;
                else                           ((bf16u*)C)[row * ldc + col] = f2b(v);
            }
        }
    }
}

// ---------------------------------------------------------------------------
// 128x128 MFMA GEMM (R7-verified single-buffer; small dispatches only).
// ---------------------------------------------------------------------------
template <typename TC>
__global__ __launch_bounds__(256) void gemm_mfma(
    const bf16u* __restrict__ A, long long sAz, int lda,
    const bf16u* __restrict__ W, long long sWz,
    const float* __restrict__ bias, long long sBz,
    TC* __restrict__ C, long long sCz, int ldc,
    int K, int act)
{
    __shared__ bf16u As[128 * 64];
    __shared__ bf16u Ws[128 * 64];

    const int z = blockIdx.z;
    A += (long long)z * sAz;
    W += (long long)z * sWz;
    C += (long long)z * sCz;
    const float* bz = bias ? (bias + (long long)z * sBz) : nullptr;

    const int gx = gridDim.x;
    const int nwg = gx * gridDim.y;
    const int orig = blockIdx.y * gx + blockIdx.x;
    const int q = nwg >> 3, rres = nwg & 7;
    const int xcd = orig & 7, loc = orig >> 3;
    const int wgid = (xcd < rres ? xcd * (q + 1) : rres * (q + 1) + (xcd - rres) * q) + loc;
    const int bm = (wgid / gx) * 128;
    const int bn = (wgid % gx) * 128;

    const int tid = threadIdx.x;
    const int lane = tid & 63;
    const int wave = tid >> 6;
    const int wr = (wave >> 1) * 64;
    const int wc = (wave & 1) * 64;
    const int l15 = lane & 15;
    const int lk8 = (lane >> 4) * 8;

    f32x4 acc[4][4];
#pragma unroll
    for (int i = 0; i < 4; ++i)
#pragma unroll
        for (int j = 0; j < 4; ++j)
#pragma unroll
            for (int r = 0; r < 4; ++r) acc[i][j][r] = 0.0f;

    const int sr = wave * 32 + (lane >> 3);
    const int sc = (lane & 7) * 8;
    const bf16u* Ag = A + (long long)(bm + sr) * lda + sc;
    const bf16u* Wg = W + (long long)(bn + sr) * K + sc;
    bf16u* Al = As + wave * 32 * 64;
    bf16u* Wl = Ws + wave * 32 * 64;

    for (int k0 = 0; k0 < K; k0 += 64) {
#pragma unroll
        for (int p = 0; p < 4; ++p) {
            __builtin_amdgcn_global_load_lds(
                (const AS1 void*)(Ag + k0 + (long long)(8 * p) * lda),
                (AS3 void*)(Al + 8 * p * 64), 16, 0, 0);
            __builtin_amdgcn_global_load_lds(
                (const AS1 void*)(Wg + k0 + (long long)(8 * p) * K),
                (AS3 void*)(Wl + 8 * p * 64), 16, 0, 0);
        }
        __syncthreads();
#pragma unroll
        for (int ks = 0; ks < 2; ++ks) {
            short8v af[4], bfr[4];
#pragma unroll
            for (int i = 0; i < 4; ++i)
                af[i] = *(const short8v*)(As + (wr + i * 16 + l15) * 64 + ks * 32 + lk8);
#pragma unroll
            for (int i = 0; i < 4; ++i)
                bfr[i] = *(const short8v*)(Ws + (wc + i * 16 + l15) * 64 + ks * 32 + lk8);
#pragma unroll
            for (int mi = 0; mi < 4; ++mi)
#pragma unroll
                for (int ni = 0; ni < 4; ++ni)
                    acc[mi][ni] = __builtin_amdgcn_mfma_f32_16x16x32_bf16(
                        af[mi], bfr[ni], acc[mi][ni], 0, 0, 0);
        }
        __syncthreads();
    }

    const int r0 = (lane >> 4) * 4;
#pragma unroll
    for (int mi = 0; mi < 4; ++mi) {
#pragma unroll
        for (int ni = 0; ni < 4; ++ni) {
            const int col = bn + wc + ni * 16 + l15;
            float badd = bz ? bz[col] : 0.0f;
#pragma unroll
            for (int r = 0; r < 4; ++r) {
                const long long row = bm + wr + mi * 16 + r0 + r;
                float v = acc[mi][ni][r] + badd;
                if (act) v = tanhf(v);
                if constexpr (sizeof(TC) == 4) ((float*)C)[row * ldc + col] = v;
                else                           ((bf16u*)C)[row * ldc + col] = f2b(v);
            }
        }
    }
}

// ---------------------------------------------------------------------------
// FUSED GRU step (R14/15/16 verified).
// ---------------------------------------------------------------------------
template <int LAYER, bool FIRST>
__global__ __launch_bounds__(256) void gru_step(
    const bf16u* __restrict__ Hb,
    const bf16u* __restrict__ Whh,
    const float* __restrict__ bhh,
    const bf16u* __restrict__ P0,
    const bf16u* __restrict__ P1,
    const float* __restrict__ bih,
    const bf16u* __restrict__ GIT,
    const float* __restrict__ hprev,
    float* __restrict__ hnext,
    bf16u* __restrict__ hnextb,
    bf16u* __restrict__ hout,
    int t, int CB)
{
    __shared__ bf16u As[2][64 * 64];
    __shared__ bf16u Ws[2][96 * 64];

    const int z = blockIdx.z;
    const int bn = blockIdx.x * 32;
    const int bm = blockIdx.y * 64;
    const int tid = threadIdx.x;
    const int lane = tid & 63;
    const int wave = tid >> 6;
    const int wm = wave >> 1;
    const int wn = wave & 1;
    const int l15 = lane & 15;
    const int lk8 = (lane >> 4) * 8;
    const int swz = (l15 & 7) << 3;

    f32x4 acc[3][2];
#pragma unroll
    for (int g = 0; g < 3; ++g)
#pragma unroll
        for (int i = 0; i < 2; ++i)
#pragma unroll
            for (int r = 0; r < 4; ++r) acc[g][i][r] = 0.0f;

    if constexpr (!FIRST) {
        const bf16u* hsrc = Hb + (long long)z * CB * 512;
        const bf16u* wsrc = Whh + (long long)z * 1536 * 512;

        const int srow = lane >> 3;
        const int sc = ((lane & 7) ^ srow) * 8;
        const bf16u* Ag = hsrc + (long long)(bm + 16 * wave + srow) * 512 + sc;
        const bf16u* Wg[3];
#pragma unroll
        for (int p = 0; p < 3; ++p) {
            const int lr = 24 * wave + 8 * p + srow;
            const int g = lr >> 5, c = lr & 31;
            Wg[p] = wsrc + (long long)(g * 512 + bn + c) * 512 + sc;
        }

        auto stage = [&](int kt, int b) {
            const long long k0 = (long long)kt << 6;
#pragma unroll
            for (int p = 0; p < 2; ++p)
                __builtin_amdgcn_global_load_lds(
                    (const AS1 void*)(Ag + k0 + (long long)(8 * p) * 512),
                    (AS3 void*)(&As[b][(16 * wave + 8 * p) * 64]), 16, 0, 0);
#pragma unroll
            for (int p = 0; p < 3; ++p)
                __builtin_amdgcn_global_load_lds(
                    (const AS1 void*)(Wg[p] + k0),
                    (AS3 void*)(&Ws[b][(24 * wave + 8 * p) * 64]), 16, 0, 0);
        };
        auto compute = [&](int b) {
#pragma unroll
            for (int ks = 0; ks < 2; ++ks) {
                const int ko = (ks * 32 + lk8) ^ swz;
                short8v af[2], bf[3];
#pragma unroll
                for (int mi = 0; mi < 2; ++mi)
                    af[mi] = *(const short8v*)(&As[b][(wm * 32 + mi * 16 + l15) * 64 + ko]);
#pragma unroll
                for (int g = 0; g < 3; ++g)
                    bf[g] = *(const short8v*)(&Ws[b][(g * 32 + wn * 16 + l15) * 64 + ko]);
                __builtin_amdgcn_s_setprio(1);
#pragma unroll
                for (int g = 0; g < 3; ++g)
#pragma unroll
                    for (int mi = 0; mi < 2; ++mi)
                        acc[g][mi] = __builtin_amdgcn_mfma_f32_16x16x32_bf16(
                            af[mi], bf[g], acc[g][mi], 0, 0, 0);
                __builtin_amdgcn_s_setprio(0);
            }
        };

        stage(0, 0);
        stage(1, 1);
        for (int kt = 0; kt < 7; ++kt) {
            asm volatile("s_waitcnt vmcnt(5)" ::: "memory");
            __builtin_amdgcn_s_barrier();
            asm volatile("" ::: "memory");
            compute(kt & 1);
            asm volatile("" ::: "memory");
            __builtin_amdgcn_s_barrier();
            if (kt + 2 < 8) stage(kt + 2, kt & 1);
        }
        asm volatile("s_waitcnt vmcnt(0)" ::: "memory");
        __builtin_amdgcn_s_barrier();
        compute(1);
    }

    const int r0 = (lane >> 4) * 4;
    const int s = z ? (SEQ - 1 - t) : t;
    float c0 = 0.0f, c1 = 0.0f;
    if (LAYER == 0) {
        float ph = 0.6283185307179586f * (float)s;
        c0 = 1.0f + 0.1f * cosf(ph);
        c1 = 0.05f * sinf(ph);
    }

    const int j = bn + wn * 16 + l15;
    const float bh0 = bhh[z * 1536 + j];
    const float bh1 = bhh[z * 1536 + 512 + j];
    const float bh2 = bhh[z * 1536 + 1024 + j];
    float bi0 = 0, bi1 = 0, bi2 = 0;
    if (LAYER == 0) {
        bi0 = bih[z * 1536 + j];
        bi1 = bih[z * 1536 + 512 + j];
        bi2 = bih[z * 1536 + 1024 + j];
    }

#pragma unroll
    for (int mi = 0; mi < 2; ++mi) {
#pragma unroll
        for (int rr = 0; rr < 4; ++rr) {
            const int m = bm + wm * 32 + mi * 16 + r0 + rr;
            float gr = acc[0][mi][rr] + bh0;
            float gz = acc[1][mi][rr] + bh1;
            float gn = acc[2][mi][rr] + bh2;
            float ir, iz, inn;
            if (LAYER == 0) {
                const bf16u* p0 = P0 + (long long)m * 3072 + z * 1536 + j;
                const bf16u* p1 = P1 + (long long)m * 3072 + z * 1536 + j;
                ir  = c0 * b2f(p0[0])    + c1 * b2f(p1[0])    + bi0;
                iz  = c0 * b2f(p0[512])  + c1 * b2f(p1[512])  + bi1;
                inn = c0 * b2f(p0[1024]) + c1 * b2f(p1[1024]) + bi2;
            } else {
                const bf16u* gi = GIT + (((long long)z * CB + m) * SEQ + s) * 1536 + j;
                ir = b2f(gi[0]); iz = b2f(gi[512]); inn = b2f(gi[1024]);
            }
            const long long ho = ((long long)z * CB + m) * 512 + j;
            float r  = fast_sigm(ir + gr);
            float zz = fast_sigm(iz + gz);
            float n  = fast_tanh(inn + r * gn);
            float hnew;
            if constexpr (FIRST) hnew = (1.0f - zz) * n;
            else                 hnew = (1.0f - zz) * n + zz * hprev[ho];
            hnext[ho]  = hnew;
            hnextb[ho] = f2b(hnew);
            hout[((long long)m * SEQ + s) * 1024 + z * 512 + j] = f2b(hnew);
        }
    }
}

__global__ void roll_b(const bf16u* __restrict__ xp, bf16u* __restrict__ rl)
{
    int idx = blockIdx.x * 256 + threadIdx.x;
    int i = idx & 511;
    int b = idx >> 9;
    rl[(size_t)b * 512 + i] = xp[(size_t)b * 512 + ((i + 511) & 511)];
}

// fused attention per (b_local, head): SEQ=10, HD=128. Writes 0.1*sum_s o
// (one 128-vec per (b,head)) — out-proj is folded across the mean (R17).
__global__ __launch_bounds__(128) void attn_kernel(const bf16u* __restrict__ qkv,
                                                   bf16u* __restrict__ osum)
{
    const int bh = blockIdx.x;
    const int h = bh & 7;
    const int bl = bh >> 3;
    const int tid = threadIdx.x;

    __shared__ float Q[SEQ][128], Kx[SEQ][128], V[SEQ][128], Amat[SEQ][SEQ];

    const bf16u* base = qkv + (size_t)bl * SEQ * 3072 + h * 128;
#pragma unroll
    for (int s = 0; s < SEQ; ++s) {
        Q[s][tid]  = b2f(base[s * 3072 + tid]);
        Kx[s][tid] = b2f(base[s * 3072 + 1024 + tid]);
        V[s][tid]  = b2f(base[s * 3072 + 2048 + tid]);
    }
    __syncthreads();

    if (tid < SEQ * SEQ) {
        int q = tid / SEQ, k = tid % SEQ;
        float acc = 0.0f;
#pragma unroll 8
        for (int d0 = 0; d0 < 128; ++d0) acc += Q[q][d0] * Kx[k][d0];
        Amat[q][k] = acc * 0.08838834764831845f;
    }
    __syncthreads();

    if (tid < SEQ) {
        float m = -1e30f;
#pragma unroll
        for (int k = 0; k < SEQ; ++k) m = fmaxf(m, Amat[tid][k]);
        float e[SEQ], ssum = 0.0f;
#pragma unroll
        for (int k = 0; k < SEQ; ++k) { e[k] = expf(Amat[tid][k] - m); ssum += e[k]; }
        float inv = 1.0f / ssum;
#pragma unroll
        for (int k = 0; k < SEQ; ++k) Amat[tid][k] = e[k] * inv;
    }
    __syncthreads();

    float os = 0.0f;
#pragma unroll
    for (int q = 0; q < SEQ; ++q) {
        float acc = 0.0f;
#pragma unroll
        for (int k = 0; k < SEQ; ++k) acc += Amat[q][k] * V[k][tid];
        os += acc;
    }
    osum[(size_t)bl * 1024 + h * 128 + tid] = f2b(0.1f * os);
}

// agg[b][j] = f2b( 0.1 * sum_s go[b][s][j] + att[b][j] ); att fp32 (incl opb)
__global__ void gmean_kernel(const bf16u* __restrict__ go, const float* __restrict__ att,
                             bf16u* __restrict__ agg)
{
    int idx = blockIdx.x * 256 + threadIdx.x;   // CB*256
    int j4 = (idx & 255) * 4;
    int bl = idx >> 8;
    const bf16u* g = go + (size_t)bl * (SEQ * 1024) + j4;
    float4 a = *(const float4*)(att + (size_t)bl * 1024 + j4);
    float s0 = 0, s1 = 0, s2 = 0, s3 = 0;
#pragma unroll
    for (int t = 0; t < SEQ; ++t) {
        ushort4 gv = *(const ushort4*)(g + t * 1024);
        s0 += b2f(gv.x); s1 += b2f(gv.y); s2 += b2f(gv.z); s3 += b2f(gv.w);
    }
    ushort4 u;
    u.x = f2b(0.1f * s0 + a.x); u.y = f2b(0.1f * s1 + a.y);
    u.z = f2b(0.1f * s2 + a.z); u.w = f2b(0.1f * s3 + a.w);
    *(ushort4*)(agg + (size_t)bl * 1024 + j4) = u;
}

extern "C" void kernel_launch(void* const* d_in, const int* in_sizes, int n_in,
                              void* d_out, int out_size, void* d_ws, size_t ws_size,
                              hipStream_t stream)
{
    const float* x    = (const float*)d_in[0];
    const float* Wp   = (const float*)d_in[1];
    const float* bp   = (const float*)d_in[2];
    const float* Wih0 = (const float*)d_in[3];
    const float* Whh0 = (const float*)d_in[4];
    const float* bih0 = (const float*)d_in[5];
    const float* bhh0 = (const float*)d_in[6];
    const float* Wih1 = (const float*)d_in[7];
    const float* Whh1 = (const float*)d_in[8];
    const float* bih1 = (const float*)d_in[9];
    const float* bhh1 = (const float*)d_in[10];
    const float* ipw  = (const float*)d_in[11];
    const float* ipb  = (const float*)d_in[12];
    const float* opw  = (const float*)d_in[13];
    const float* opb  = (const float*)d_in[14];
    const float* W1   = (const float*)d_in[15];
    const float* b1   = (const float*)d_in[16];
    const float* W2   = (const float*)d_in[17];
    const float* b2   = (const float*)d_in[18];
    float* out = (float*)d_out;

    const long long WOVER = 9437184LL;
    const long long WALL  = 24969216LL;
    int CB = 0;
    for (int c = 4096; c >= 128; c >>= 1)
        if (WOVER + (long long)c * 114688 <= (long long)ws_size) { CB = c; break; }
    if (CB == 0) return;
    const bool resident = (WALL + (long long)CB * 114688 <= (long long)ws_size);
    const long long WB = resident ? WALL : WOVER;

    bf16u* wreg = (bf16u*)d_ws;
    bf16u *Wpb, *Wih0b, *Whh0b, *Wih1b, *Whh1b, *ipwb, *opwb, *W1b, *W2b;
    if (resident) {
        Wpb   = wreg;
        Wih0b = wreg + 262144;
        Whh0b = wreg + 1835008;
        Wih1b = wreg + 3407872;
        Whh1b = wreg + 6553600;
        ipwb  = wreg + 8126464;
        opwb  = wreg + 11272192;
        W1b   = wreg + 12320768;
        W2b   = wreg + 12451840;
    } else {
        Wpb   = wreg;
        Wih0b = wreg + 262144;
        Whh0b = wreg + 1835008;
        Wih1b = wreg;
        Whh1b = wreg + 3145728;
        ipwb  = wreg;
        opwb  = wreg + 3145728;
        W1b   = wreg + 4194304;
        W2b   = wreg + 4325376;
    }

    char* A0 = (char*)d_ws + WB;
    bf16u* H1c = (bf16u*)A0;
    bf16u* GOc = (bf16u*)(A0 + 20480LL * CB);
    char*  U   = A0 + 40960LL * CB;
    bf16u* P0    = (bf16u*)U;
    bf16u* P1    = (bf16u*)(U + 6144LL * CB);
    bf16u* XB    = (bf16u*)(U + 12288LL * CB);
    bf16u* XPb   = (bf16u*)(U + 13312LL * CB);
    bf16u* RLb   = (bf16u*)(U + 14336LL * CB);
    bf16u* GIT   = (bf16u*)U;
    char*  HC    = U + 61440LL * CB;
    bf16u* QKV   = (bf16u*)U;
    bf16u* OSUMb = (bf16u*)(U + 61440LL * CB);      // CB*1024 bf16
    float* ATT   = (float*)A0;                      // CB*1024 f32 (H1c dead)
    bf16u* AGGb  = (bf16u*)(A0 + 10240LL * CB);
    bf16u* HIDb  = (bf16u*)(A0 + 12288LL * CB);

    const dim3 blk(256);
    const int MB = CB / 128;

    auto cvt = [&](const float* s, bf16u* d, long long nfloats) {
        int n4 = (int)(nfloats / 4);
        cvt_f2b<<<(n4 + 255) / 256, blk, 0, stream>>>(s, d, n4);
    };

    if (resident) {
        cvt(Wp,   Wpb,   512LL * 512);
        cvt(Wih0, Wih0b, 2LL * 1536 * 512);
        cvt(Whh0, Whh0b, 2LL * 1536 * 512);
        cvt(Wih1, Wih1b, 2LL * 1536 * 1024);
        cvt(Whh1, Whh1b, 2LL * 1536 * 512);
        cvt(ipw,  ipwb,  3072LL * 1024);
        cvt(opw,  opwb,  1024LL * 1024);
        cvt(W1,   W1b,   128LL * 1024);
        cvt(W2,   W2b,   256LL * 128);
    }

    for (int c0 = 0; c0 < 4096; c0 += CB) {
        // ---------------- phase A: preproc + layer-0 biGRU ----------------
        cvt(x + (long long)c0 * 512, XB, (long long)CB * 512);
        if (!resident) {
            cvt(Wp,   Wpb,   512LL * 512);
            cvt(Wih0, Wih0b, 2LL * 1536 * 512);
            cvt(Whh0, Whh0b, 2LL * 1536 * 512);
        }

        gemm_mfma<bf16u><<<dim3(4, MB, 1), blk, 0, stream>>>(
            XB, 0, 512, Wpb, 0, bp, 0, XPb, 0, 512, 512, 0);
        roll_b<<<CB * 2, blk, 0, stream>>>(XPb, RLb);
        gemm_mfma128p<bf16u><<<dim3(24, MB, 2), blk, 0, stream>>>(
            XPb, (long long)CB * 512, 512, Wih0b, 0, nullptr, 0,
            P0, (long long)CB * 3072, 3072, 512, 0);

        for (int t = 0; t < SEQ; ++t) {
            const int rb = t & 1;
            float* hprev  = (float*)(HC + (long long)rb * 6144 * CB);
            bf16u* Hbr    = (bf16u*)(HC + (long long)rb * 6144 * CB + 4096LL * CB);
            float* hnext  = (float*)(HC + (long long)(1 - rb) * 6144 * CB);
            bf16u* hnextb = (bf16u*)(HC + (long long)(1 - rb) * 6144 * CB + 4096LL * CB);
            if (t == 0)
                gru_step<0, true><<<dim3(16, CB / 64, 2), blk, 0, stream>>>(
                    Hbr, Whh0b, bhh0, P0, P1, bih0, nullptr,
                    hprev, hnext, hnextb, H1c, t, CB);
            else
                gru_step<0, false><<<dim3(16, CB / 64, 2), blk, 0, stream>>>(
                    Hbr, Whh0b, bhh0, P0, P1, bih0, nullptr,
                    hprev, hnext, hnextb, H1c, t, CB);
        }

        // ---------------- phase B: layer-1 biGRU ----------------
        if (!resident) {
            cvt(Wih1, Wih1b, 2LL * 1536 * 1024);
            cvt(Whh1, Whh1b, 2LL * 1536 * 512);
        }
        gemm_mfma256<bf16u><<<dim3(6, CB * 10 / 256, 2), dim3(512), 0, stream>>>(
            H1c, 0, 1024, Wih1b, 1536LL * 1024, bih1, 1536,
            GIT, (long long)CB * SEQ * 1536, 1536, 1024, 0);

        for (int t = 0; t < SEQ; ++t) {
            const int rb = t & 1;
            float* hprev  = (float*)(HC + (long long)rb * 6144 * CB);
            bf16u* Hbr    = (bf16u*)(HC + (long long)rb * 6144 * CB + 4096LL * CB);
            float* hnext  = (float*)(HC + (long long)(1 - rb) * 6144 * CB);
            bf16u* hnextb = (bf16u*)(HC + (long long)(1 - rb) * 6144 * CB + 4096LL * CB);
            if (t == 0)
                gru_step<1, true><<<dim3(16, CB / 64, 2), blk, 0, stream>>>(
                    Hbr, Whh1b, bhh1, nullptr, nullptr, nullptr, GIT,
                    hprev, hnext, hnextb, GOc, t, CB);
            else
                gru_step<1, false><<<dim3(16, CB / 64, 2), blk, 0, stream>>>(
                    Hbr, Whh1b, bhh1, nullptr, nullptr, nullptr, GIT,
                    hprev, hnext, hnextb, GOc, t, CB);
        }

        // ---------------- phase C: attention + head ----------------
        if (!resident) {
            cvt(ipw, ipwb, 3072LL * 1024);
            cvt(opw, opwb, 1024LL * 1024);
            cvt(W1,  W1b,  128LL * 1024);
            cvt(W2,  W2b,  256LL * 128);
        }
        gemm_mfma256<bf16u><<<dim3(12, CB * 10 / 256, 1), dim3(512), 0, stream>>>(
            GOc, 0, 1024, ipwb, 0, ipb, 0, QKV, 0, 3072, 1024, 0);
        attn_kernel<<<CB * 8, dim3(128), 0, stream>>>(QKV, OSUMb);
        // ATT = OSUM @ opw^T + opb   (M=CB, N=1024, K=1024; 10x smaller)
        gemm_mfma128p<float><<<dim3(8, MB, 1), blk, 0, stream>>>(
            OSUMb, 0, 1024, opwb, 0, opb, 0, ATT, 0, 1024, 1024, 0);
        gmean_kernel<<<CB, blk, 0, stream>>>(GOc, ATT, AGGb);
        gemm_mfma<bf16u><<<dim3(1, MB, 1), blk, 0, stream>>>(
            AGGb, 0, 1024, W1b, 0, b1, 0, HIDb, 0, 128, 1024, 1);
        gemm_mfma<float><<<dim3(2, MB, 1), blk, 0, stream>>>(
            HIDb, 0, 128, W2b, 0, b2, 0, out + (long long)c0 * 256, 0, 256, 128, 0);
    }
}